// Round 4
// baseline (779.684 us; speedup 1.0000x reference)
//
#include <hip/hip_runtime.h>
#include <hip/hip_bf16.h>

typedef __hip_bfloat16 bf16;

#define HW 16384

__device__ __forceinline__ float b2f(bf16 v) { return __bfloat162float(v); }
__device__ __forceinline__ bf16 f2b(float v) { return __float2bfloat16(v); }

// ---- ws byte offsets (total 41 MiB, proven safe in R3) ----
#define OFFB_XP    0u                 // fp32 131072            (0.5 MiB)
#define OFFB_K2    524288u            // fp32 65536             (0.25 MiB)
#define OFFB_V2    786432u            // fp32 65536             (0.25 MiB) -> 1 MiB
#define OFFB_QKVG  (1u << 20)         // bf16 (b,256,HW): ch 0-63 q, 64-127 k, 128-191 v, 192-255 qg
                                      //   = 32 MiB -> ends at 33 MiB. qg ch overwritten in-place by res_l.
#define OFFB_RESH  (33u << 20)        // bf16 (b,64,HW) = 8 MiB -> 41 MiB
// p / v-hat scratch live in d_out (32 MiB fp32): bytes [0,8MiB) p bf16, [8MiB,16MiB) v bf16;
// d_out is fully overwritten by k_proj before validation.

// ---------------- 8x8 avgpool: x fp32 -> xp fp32 ----------------
__global__ __launch_bounds__(256) void k_pool(const float* __restrict__ x, float* __restrict__ xp)
{
    int idx = blockIdx.x * 256 + threadIdx.x;   // 131072 total
    int j = idx & 15, i = (idx >> 4) & 15, bc = idx >> 8;
    const float* src = x + (size_t)bc * HW + (i * 8) * 128 + j * 8;
    float s = 0.f;
    #pragma unroll
    for (int u = 0; u < 8; u++) {
        #pragma unroll
        for (int t = 0; t < 8; t++) s += src[u * 128 + t];
    }
    xp[bc * 256 + i * 16 + j] = s * (1.f / 64.f);
}

// ---------------- kv conv: xp -> k2/v2 fp32 (b,h,m,d) ----------------
__global__ __launch_bounds__(256) void k_kv(const float* __restrict__ xp,
                                            const float* __restrict__ Wkv, const float* __restrict__ bkv,
                                            float* __restrict__ k2, float* __restrict__ v2)
{
    int og = blockIdx.x & 15, b = blockIdx.x >> 4;
    int m = threadIdx.x;
    float xr[128];
    #pragma unroll
    for (int c = 0; c < 128; c++) xr[c] = xp[(b * 128 + c) * 256 + m];
    #pragma unroll 1
    for (int t = 0; t < 8; t++) {
        int o = og * 8 + t;
        const float* w = Wkv + o * 128;
        float s0 = 0.f, s1 = 0.f, s2 = 0.f, s3 = 0.f;
        #pragma unroll
        for (int c = 0; c < 128; c += 4) {
            s0 += w[c] * xr[c]; s1 += w[c + 1] * xr[c + 1];
            s2 += w[c + 2] * xr[c + 2]; s3 += w[c + 3] * xr[c + 3];
        }
        float a = bkv[o] + ((s0 + s1) + (s2 + s3));
        int sb = o >> 6, r = o & 63, gh = r >> 4, dh = r & 15;
        float* dst = sb == 0 ? k2 : v2;
        dst[((b * 4 + gh) * 256 + m) * 16 + dh] = a;
    }
}

// ---------------- fused conv1x1: x -> qkvg bf16 (b,256,HW). grid 1024, 64-px LDS tiles ----
// thread = (q = tid>>6 channel-quadrant [wave-uniform], px = tid&63)
__global__ __launch_bounds__(256) void k_conv(const float* __restrict__ x,
                                              const float* __restrict__ Wqkv, const float* __restrict__ bqkv,
                                              const float* __restrict__ Wq,  const float* __restrict__ bq,
                                              bf16* __restrict__ qkvg)
{
    __shared__ float xs[128 * 64];
    int tid = threadIdx.x;
    int b = blockIdx.x >> 8, tile = blockIdx.x & 255;
    int px0 = tile * 64;
    const float* xb = x + (size_t)b * 128 * HW + px0;
    #pragma unroll
    for (int i = 0; i < 32; i++) {
        int c = i * 4 + (tid >> 6), px = tid & 63;
        xs[c * 64 + px] = xb[(size_t)c * HW + px];
    }
    __syncthreads();
    int q = tid >> 6, px = tid & 63;
    float xr[128];
    #pragma unroll
    for (int c = 0; c < 128; c++) xr[c] = xs[c * 64 + px];
    const float* W; const float* bias;
    if (q < 3) { W = Wqkv + q * 64 * 128; bias = bqkv + q * 64; }
    else       { W = Wq;                  bias = bq; }
    bf16* outp = qkvg + (size_t)(b * 256 + q * 64) * HW + px0 + px;
    #pragma unroll 1
    for (int og = 0; og < 16; og++) {
        int o = og * 4;
        float a0 = bias[o], a1 = bias[o + 1], a2 = bias[o + 2], a3 = bias[o + 3];
        const float* w0 = W + (o + 0) * 128;
        const float* w1 = W + (o + 1) * 128;
        const float* w2 = W + (o + 2) * 128;
        const float* w3 = W + (o + 3) * 128;
        #pragma unroll
        for (int c = 0; c < 128; c++) {
            float xv = xr[c];
            a0 += w0[c] * xv; a1 += w1[c] * xv; a2 += w2[c] * xv; a3 += w3[c] * xv;
        }
        outp[(size_t)(o + 0) * HW] = f2b(a0); outp[(size_t)(o + 1) * HW] = f2b(a1);
        outp[(size_t)(o + 2) * HW] = f2b(a2); outp[(size_t)(o + 3) * HW] = f2b(a3);
    }
}

// ---------------- depthwise 3x3 + q*k: qkvg -> p, v-hat (bf16, scratch in d_out) ----------
__global__ __launch_bounds__(256) void k_dw(const bf16* __restrict__ qkvg,
                                            const float* __restrict__ Wdw, const float* __restrict__ bdw,
                                            bf16* __restrict__ p, bf16* __restrict__ v)
{
    int nblk = blockIdx.x & 63;
    int bc = blockIdx.x >> 6;       // 0..255
    int c = bc & 63, b = bc >> 6;
    int n = nblk * 256 + threadIdx.x;
    int i = n >> 7, j = n & 127;
    const bf16* in0 = qkvg + (size_t)(b * 256 + c) * HW;
    const bf16* in1 = qkvg + (size_t)(b * 256 + 64 + c) * HW;
    const bf16* in2 = qkvg + (size_t)(b * 256 + 128 + c) * HW;
    float aq = bdw[c], ak = bdw[64 + c], av = bdw[128 + c];
    #pragma unroll
    for (int dy = 0; dy < 3; dy++) {
        int ii = i + dy - 1;
        bool iv = (unsigned)ii < 128u;
        #pragma unroll
        for (int dx = 0; dx < 3; dx++) {
            int jj = j + dx - 1;
            bool ok = iv && ((unsigned)jj < 128u);
            int off = ii * 128 + jj;
            float q0 = ok ? b2f(in0[off]) : 0.f;
            float k0 = ok ? b2f(in1[off]) : 0.f;
            float v0 = ok ? b2f(in2[off]) : 0.f;
            int t = dy * 3 + dx;
            aq += Wdw[c * 9 + t] * q0;
            ak += Wdw[(64 + c) * 9 + t] * k0;
            av += Wdw[(128 + c) * 9 + t] * v0;
        }
    }
    p[(size_t)(b * 64 + c) * HW + n] = f2b(aq * ak);
    v[(size_t)(b * 64 + c) * HW + n] = f2b(av);
}

// ---------------- low-freq attention, LDS-staged K/V. grid (64,4,4) ----------------
__global__ __launch_bounds__(256) void k_attn(bf16* __restrict__ qkvg, const float* __restrict__ k2,
                                              const float* __restrict__ v2)
{
    __shared__ float4 kf[1024];
    __shared__ float4 vf[1024];
    int tid = threadIdx.x;
    int h = blockIdx.y, b = blockIdx.z;
    const float4* kb = (const float4*)(k2 + (size_t)(b * 4 + h) * 4096);
    const float4* vb = (const float4*)(v2 + (size_t)(b * 4 + h) * 4096);
    #pragma unroll
    for (int i = 0; i < 4; i++) {
        kf[i * 256 + tid] = kb[i * 256 + tid];
        vf[i * 256 + tid] = vb[i * 256 + tid];
    }
    __syncthreads();
    int n = blockIdx.x * 256 + tid;
    bf16* qp = qkvg + (size_t)(b * 256 + 192 + h * 16) * HW + n;
    float qv[16];
    #pragma unroll
    for (int d = 0; d < 16; d++) qv[d] = b2f(qp[(size_t)d * HW]) * 0.25f;
    float o[16];
    #pragma unroll
    for (int d = 0; d < 16; d++) o[d] = 0.f;
    float den = 0.f;
    #pragma unroll 2
    for (int m = 0; m < 256; m++) {
        float4 ka = kf[m * 4 + 0], kb1 = kf[m * 4 + 1], kc = kf[m * 4 + 2], kd = kf[m * 4 + 3];
        float s0 = qv[0] * ka.x + qv[1] * ka.y + qv[2] * ka.z + qv[3] * ka.w;
        float s1 = qv[4] * kb1.x + qv[5] * kb1.y + qv[6] * kb1.z + qv[7] * kb1.w;
        float s2 = qv[8] * kc.x + qv[9] * kc.y + qv[10] * kc.z + qv[11] * kc.w;
        float s3 = qv[12] * kd.x + qv[13] * kd.y + qv[14] * kd.z + qv[15] * kd.w;
        float s = (s0 + s1) + (s2 + s3);
        s = fminf(fmaxf(s, -60.f), 60.f);
        float e = __expf(s);
        den += e;
        float4 va = vf[m * 4 + 0], vb1 = vf[m * 4 + 1], vc = vf[m * 4 + 2], vd = vf[m * 4 + 3];
        o[0] += e * va.x;  o[1] += e * va.y;  o[2] += e * va.z;  o[3] += e * va.w;
        o[4] += e * vb1.x; o[5] += e * vb1.y; o[6] += e * vb1.z; o[7] += e * vb1.w;
        o[8] += e * vc.x;  o[9] += e * vc.y;  o[10] += e * vc.z; o[11] += e * vc.w;
        o[12] += e * vd.x; o[13] += e * vd.y; o[14] += e * vd.z; o[15] += e * vd.w;
    }
    float r = 1.f / den;
    #pragma unroll
    for (int d = 0; d < 16; d++) qp[(size_t)d * HW] = f2b(o[d] * r);
}

// ---------------- high-freq gate: p,v-hat -> res_h bf16. grid 1024, 64-px LDS tiles ------
__global__ __launch_bounds__(256) void k_resh(const bf16* __restrict__ p, const bf16* __restrict__ v,
                                              const float* __restrict__ Wa1, const float* __restrict__ ba1,
                                              const float* __restrict__ Wa2, const float* __restrict__ ba2,
                                              bf16* __restrict__ resh)
{
    __shared__ float ps[64 * 64];
    __shared__ float ss[64 * 64];
    int tid = threadIdx.x;
    int b = blockIdx.x >> 8, tile = blockIdx.x & 255;
    int px0 = tile * 64;
    const bf16* pb = p + (size_t)b * 64 * HW + px0;
    #pragma unroll
    for (int i = 0; i < 16; i++) {
        int c = i * 4 + (tid >> 6), px = tid & 63;
        ps[c * 64 + px] = b2f(pb[(size_t)c * HW + px]);
    }
    __syncthreads();
    int q = tid >> 6, px = tid & 63;
    float pr[64];
    #pragma unroll
    for (int c = 0; c < 64; c++) pr[c] = ps[c * 64 + px];
    #pragma unroll 1
    for (int o = 0; o < 16; o++) {
        int oc = q * 16 + o;
        const float* w = Wa1 + oc * 64;
        float s0 = 0.f, s1 = 0.f, s2 = 0.f, s3 = 0.f;
        #pragma unroll
        for (int c = 0; c < 64; c += 4) {
            s0 += w[c] * pr[c]; s1 += w[c + 1] * pr[c + 1];
            s2 += w[c + 2] * pr[c + 2]; s3 += w[c + 3] * pr[c + 3];
        }
        float a = ba1[oc] + ((s0 + s1) + (s2 + s3));
        ss[oc * 64 + px] = a / (1.f + __expf(-a));   // swish
    }
    __syncthreads();
    float sr[64];
    #pragma unroll
    for (int c = 0; c < 64; c++) sr[c] = ss[c * 64 + px];
    #pragma unroll 1
    for (int o = 0; o < 16; o++) {
        int oc = q * 16 + o;
        const float* w = Wa2 + oc * 64;
        float s0 = 0.f, s1 = 0.f, s2 = 0.f, s3 = 0.f;
        #pragma unroll
        for (int c = 0; c < 64; c += 4) {
            s0 += w[c] * sr[c]; s1 += w[c + 1] * sr[c + 1];
            s2 += w[c + 2] * sr[c + 2]; s3 += w[c + 3] * sr[c + 3];
        }
        float acc = ba2[oc] + ((s0 + s1) + (s2 + s3));
        float g = tanhf(acc * 0.25f);
        float vv = b2f(v[(size_t)(b * 64 + oc) * HW + px0 + px]);
        resh[(size_t)(b * 64 + oc) * HW + px0 + px] = f2b(g * vv);
    }
}

// ---------------- final proj: [res_h | res_l] -> out fp32. grid 1024, 64-px LDS tiles ----
__global__ __launch_bounds__(256) void k_proj(const bf16* __restrict__ resh, const bf16* __restrict__ qkvg,
                                              const float* __restrict__ Wproj, const float* __restrict__ bproj,
                                              float* __restrict__ out)
{
    __shared__ float cs[128 * 64];
    int tid = threadIdx.x;
    int b = blockIdx.x >> 8, tile = blockIdx.x & 255;
    int px0 = tile * 64;
    const bf16* rh = resh + (size_t)b * 64 * HW + px0;
    const bf16* rl = qkvg + (size_t)(b * 256 + 192) * HW + px0;
    #pragma unroll
    for (int i = 0; i < 16; i++) {
        int c = i * 4 + (tid >> 6), px = tid & 63;
        cs[c * 64 + px] = b2f(rh[(size_t)c * HW + px]);
        cs[(64 + c) * 64 + px] = b2f(rl[(size_t)c * HW + px]);
    }
    __syncthreads();
    int q = tid >> 6, px = tid & 63;
    float xr[128];
    #pragma unroll
    for (int c = 0; c < 128; c++) xr[c] = cs[c * 64 + px];
    float* outp = out + (size_t)(b * 128 + q * 32) * HW + px0 + px;
    const float* W = Wproj + q * 32 * 128;
    const float* bias = bproj + q * 32;
    #pragma unroll 1
    for (int og = 0; og < 8; og++) {
        int o = og * 4;
        float a0 = bias[o], a1 = bias[o + 1], a2 = bias[o + 2], a3 = bias[o + 3];
        const float* w0 = W + (o + 0) * 128;
        const float* w1 = W + (o + 1) * 128;
        const float* w2 = W + (o + 2) * 128;
        const float* w3 = W + (o + 3) * 128;
        #pragma unroll
        for (int c = 0; c < 128; c++) {
            float xv = xr[c];
            a0 += w0[c] * xv; a1 += w1[c] * xv; a2 += w2[c] * xv; a3 += w3[c] * xv;
        }
        outp[(size_t)(o + 0) * HW] = a0; outp[(size_t)(o + 1) * HW] = a1;
        outp[(size_t)(o + 2) * HW] = a2; outp[(size_t)(o + 3) * HW] = a3;
    }
}

extern "C" void kernel_launch(void* const* d_in, const int* in_sizes, int n_in,
                              void* d_out, int out_size, void* d_ws, size_t ws_size,
                              hipStream_t stream)
{
    (void)in_sizes; (void)n_in; (void)out_size; (void)ws_size;
    const float* x     = (const float*)d_in[0];
    const float* Wqkv  = (const float*)d_in[1];
    const float* bqkv  = (const float*)d_in[2];
    const float* Wdw   = (const float*)d_in[3];
    const float* bdw   = (const float*)d_in[4];
    const float* Wa1   = (const float*)d_in[5];
    const float* ba1   = (const float*)d_in[6];
    const float* Wa2   = (const float*)d_in[7];
    const float* ba2   = (const float*)d_in[8];
    const float* Wq    = (const float*)d_in[9];
    const float* bq    = (const float*)d_in[10];
    const float* Wkv   = (const float*)d_in[11];
    const float* bkv   = (const float*)d_in[12];
    const float* Wproj = (const float*)d_in[13];
    const float* bproj = (const float*)d_in[14];

    char* wsb = (char*)d_ws;
    float* xp   = (float*)(wsb + OFFB_XP);
    float* k2   = (float*)(wsb + OFFB_K2);
    float* v2   = (float*)(wsb + OFFB_V2);
    bf16*  qkvg = (bf16*)(wsb + OFFB_QKVG);
    bf16*  resh = (bf16*)(wsb + OFFB_RESH);
    bf16*  p    = (bf16*)d_out;                  // scratch in d_out, dead before k_proj
    bf16*  v    = (bf16*)d_out + 4194304;
    float* out  = (float*)d_out;

    k_pool<<<dim3(512), 256, 0, stream>>>(x, xp);
    k_kv<<<dim3(64), 256, 0, stream>>>(xp, Wkv, bkv, k2, v2);
    k_conv<<<dim3(1024), 256, 0, stream>>>(x, Wqkv, bqkv, Wq, bq, qkvg);
    k_dw<<<dim3(16384), 256, 0, stream>>>(qkvg, Wdw, bdw, p, v);
    k_attn<<<dim3(64, 4, 4), 256, 0, stream>>>(qkvg, k2, v2);       // res_l in-place over qg ch
    k_resh<<<dim3(1024), 256, 0, stream>>>(p, v, Wa1, ba1, Wa2, ba2, resh);
    k_proj<<<dim3(1024), 256, 0, stream>>>(resh, qkvg, Wproj, bproj, out);
}

// Round 5
// 508.085 us; speedup vs baseline: 1.5346x; 1.5346x over previous
//
#include <hip/hip_runtime.h>
#include <hip/hip_bf16.h>

typedef __hip_bfloat16 bf16;

#define HW 16384

__device__ __forceinline__ float b2f(bf16 v) { return __bfloat162float(v); }
__device__ __forceinline__ bf16 f2b(float v) { return __float2bfloat16(v); }
// wave-uniform value -> SGPR so weight pointers become scalar (s_load) instead of per-lane
__device__ __forceinline__ int wuniform(int v) { return __builtin_amdgcn_readfirstlane(v); }

// ---- ws byte offsets (total 41 MiB, proven safe in R3/R4) ----
#define OFFB_XP    0u                 // fp32 131072            (0.5 MiB)
#define OFFB_K2    524288u            // fp32 65536             (0.25 MiB)
#define OFFB_V2    786432u            // fp32 65536             (0.25 MiB) -> 1 MiB
#define OFFB_QKVG  (1u << 20)         // bf16 (b,256,HW): ch 0-63 q, 64-127 k, 128-191 v, 192-255 qg
                                      //   = 32 MiB -> ends at 33 MiB. qg ch overwritten in-place by res_l.
#define OFFB_RESH  (33u << 20)        // bf16 (b,64,HW) = 8 MiB -> 41 MiB
// p / v-hat scratch live in d_out (32 MiB fp32): [0,8MiB) p bf16, [8MiB,16MiB) v bf16;
// d_out fully overwritten by k_proj before validation.

// ---------------- 8x8 avgpool: x fp32 -> xp fp32 ----------------
__global__ __launch_bounds__(256) void k_pool(const float* __restrict__ x, float* __restrict__ xp)
{
    int idx = blockIdx.x * 256 + threadIdx.x;   // 131072 total
    int j = idx & 15, i = (idx >> 4) & 15, bc = idx >> 8;
    const float* src = x + (size_t)bc * HW + (i * 8) * 128 + j * 8;
    float s = 0.f;
    #pragma unroll
    for (int u = 0; u < 8; u++) {
        #pragma unroll
        for (int t = 0; t < 8; t++) s += src[u * 128 + t];
    }
    xp[bc * 256 + i * 16 + j] = s * (1.f / 64.f);
}

// ---------------- kv conv: xp -> k2/v2 fp32 (b,h,m,d) ----------------
__global__ __launch_bounds__(256) void k_kv(const float* __restrict__ xp,
                                            const float* __restrict__ Wkv, const float* __restrict__ bkv,
                                            float* __restrict__ k2, float* __restrict__ v2)
{
    int og = blockIdx.x & 15, b = blockIdx.x >> 4;
    int m = threadIdx.x;
    float xr[128];
    #pragma unroll
    for (int c = 0; c < 128; c++) xr[c] = xp[(b * 128 + c) * 256 + m];
    #pragma unroll 1
    for (int t = 0; t < 8; t++) {
        int o = og * 8 + t;
        const float* w = Wkv + o * 128;
        float s0 = 0.f, s1 = 0.f, s2 = 0.f, s3 = 0.f;
        #pragma unroll
        for (int c = 0; c < 128; c += 4) {
            s0 += w[c] * xr[c]; s1 += w[c + 1] * xr[c + 1];
            s2 += w[c + 2] * xr[c + 2]; s3 += w[c + 3] * xr[c + 3];
        }
        float a = bkv[o] + ((s0 + s1) + (s2 + s3));
        int sb = o >> 6, r = o & 63, gh = r >> 4, dh = r & 15;
        float* dst = sb == 0 ? k2 : v2;
        dst[((b * 4 + gh) * 256 + m) * 16 + dh] = a;
    }
}

// ---------------- fused conv1x1: x -> qkvg bf16 (b,256,HW). grid 1024, 64-px LDS tiles ----
// q = wave-uniform channel-quadrant (forced to SGPR -> scalar weight loads)
__global__ __launch_bounds__(256) void k_conv(const float* __restrict__ x,
                                              const float* __restrict__ Wqkv, const float* __restrict__ bqkv,
                                              const float* __restrict__ Wq,  const float* __restrict__ bq,
                                              bf16* __restrict__ qkvg)
{
    __shared__ float xs[128 * 64];
    int tid = threadIdx.x;
    int b = blockIdx.x >> 8, tile = blockIdx.x & 255;
    int px0 = tile * 64;
    const float* xb = x + (size_t)b * 128 * HW + px0;
    #pragma unroll
    for (int i = 0; i < 32; i++) {
        int c = i * 4 + (tid >> 6), px = tid & 63;
        xs[c * 64 + px] = xb[(size_t)c * HW + px];
    }
    __syncthreads();
    int q = wuniform(tid >> 6);      // SGPR: weight pointers become wave-uniform
    int px = tid & 63;
    float xr[128];
    #pragma unroll
    for (int c = 0; c < 128; c++) xr[c] = xs[c * 64 + px];
    const float* W; const float* bias;
    if (q < 3) { W = Wqkv + q * 64 * 128; bias = bqkv + q * 64; }
    else       { W = Wq;                  bias = bq; }
    bf16* outp = qkvg + (size_t)(b * 256 + q * 64) * HW + px0 + px;
    #pragma unroll 1
    for (int og = 0; og < 16; og++) {
        int o = og * 4;
        float a0 = bias[o], a1 = bias[o + 1], a2 = bias[o + 2], a3 = bias[o + 3];
        const float* w0 = W + (o + 0) * 128;
        const float* w1 = W + (o + 1) * 128;
        const float* w2 = W + (o + 2) * 128;
        const float* w3 = W + (o + 3) * 128;
        #pragma unroll
        for (int c = 0; c < 128; c++) {
            float xv = xr[c];
            a0 += w0[c] * xv; a1 += w1[c] * xv; a2 += w2[c] * xv; a3 += w3[c] * xv;
        }
        outp[(size_t)(o + 0) * HW] = f2b(a0); outp[(size_t)(o + 1) * HW] = f2b(a1);
        outp[(size_t)(o + 2) * HW] = f2b(a2); outp[(size_t)(o + 3) * HW] = f2b(a3);
    }
}

// ---------------- depthwise 3x3 + q*k: qkvg -> p, v-hat (bf16, scratch in d_out) ----------
__global__ __launch_bounds__(256) void k_dw(const bf16* __restrict__ qkvg,
                                            const float* __restrict__ Wdw, const float* __restrict__ bdw,
                                            bf16* __restrict__ p, bf16* __restrict__ v)
{
    int nblk = blockIdx.x & 63;
    int bc = blockIdx.x >> 6;       // 0..255
    int c = bc & 63, b = bc >> 6;
    int n = nblk * 256 + threadIdx.x;
    int i = n >> 7, j = n & 127;
    const bf16* in0 = qkvg + (size_t)(b * 256 + c) * HW;
    const bf16* in1 = qkvg + (size_t)(b * 256 + 64 + c) * HW;
    const bf16* in2 = qkvg + (size_t)(b * 256 + 128 + c) * HW;
    float aq = bdw[c], ak = bdw[64 + c], av = bdw[128 + c];
    #pragma unroll
    for (int dy = 0; dy < 3; dy++) {
        int ii = i + dy - 1;
        bool iv = (unsigned)ii < 128u;
        #pragma unroll
        for (int dx = 0; dx < 3; dx++) {
            int jj = j + dx - 1;
            bool ok = iv && ((unsigned)jj < 128u);
            int off = ii * 128 + jj;
            float q0 = ok ? b2f(in0[off]) : 0.f;
            float k0 = ok ? b2f(in1[off]) : 0.f;
            float v0 = ok ? b2f(in2[off]) : 0.f;
            int t = dy * 3 + dx;
            aq += Wdw[c * 9 + t] * q0;
            ak += Wdw[(64 + c) * 9 + t] * k0;
            av += Wdw[(128 + c) * 9 + t] * v0;
        }
    }
    p[(size_t)(b * 64 + c) * HW + n] = f2b(aq * ak);
    v[(size_t)(b * 64 + c) * HW + n] = f2b(av);
}

// ---------------- low-freq attention, LDS-staged K/V. grid (64,4,4) ----------------
__global__ __launch_bounds__(256) void k_attn(bf16* __restrict__ qkvg, const float* __restrict__ k2,
                                              const float* __restrict__ v2)
{
    __shared__ float4 kf[1024];
    __shared__ float4 vf[1024];
    int tid = threadIdx.x;
    int h = blockIdx.y, b = blockIdx.z;
    const float4* kb = (const float4*)(k2 + (size_t)(b * 4 + h) * 4096);
    const float4* vb = (const float4*)(v2 + (size_t)(b * 4 + h) * 4096);
    #pragma unroll
    for (int i = 0; i < 4; i++) {
        kf[i * 256 + tid] = kb[i * 256 + tid];
        vf[i * 256 + tid] = vb[i * 256 + tid];
    }
    __syncthreads();
    int n = blockIdx.x * 256 + tid;
    bf16* qp = qkvg + (size_t)(b * 256 + 192 + h * 16) * HW + n;
    float qv[16];
    #pragma unroll
    for (int d = 0; d < 16; d++) qv[d] = b2f(qp[(size_t)d * HW]) * 0.25f;
    float o[16];
    #pragma unroll
    for (int d = 0; d < 16; d++) o[d] = 0.f;
    float den = 0.f;
    #pragma unroll 2
    for (int m = 0; m < 256; m++) {
        float4 ka = kf[m * 4 + 0], kb1 = kf[m * 4 + 1], kc = kf[m * 4 + 2], kd = kf[m * 4 + 3];
        float s0 = qv[0] * ka.x + qv[1] * ka.y + qv[2] * ka.z + qv[3] * ka.w;
        float s1 = qv[4] * kb1.x + qv[5] * kb1.y + qv[6] * kb1.z + qv[7] * kb1.w;
        float s2 = qv[8] * kc.x + qv[9] * kc.y + qv[10] * kc.z + qv[11] * kc.w;
        float s3 = qv[12] * kd.x + qv[13] * kd.y + qv[14] * kd.z + qv[15] * kd.w;
        float s = (s0 + s1) + (s2 + s3);
        s = fminf(fmaxf(s, -60.f), 60.f);
        float e = __expf(s);
        den += e;
        float4 va = vf[m * 4 + 0], vb1 = vf[m * 4 + 1], vc = vf[m * 4 + 2], vd = vf[m * 4 + 3];
        o[0] += e * va.x;  o[1] += e * va.y;  o[2] += e * va.z;  o[3] += e * va.w;
        o[4] += e * vb1.x; o[5] += e * vb1.y; o[6] += e * vb1.z; o[7] += e * vb1.w;
        o[8] += e * vc.x;  o[9] += e * vc.y;  o[10] += e * vc.z; o[11] += e * vc.w;
        o[12] += e * vd.x; o[13] += e * vd.y; o[14] += e * vd.z; o[15] += e * vd.w;
    }
    float r = 1.f / den;
    #pragma unroll
    for (int d = 0; d < 16; d++) qp[(size_t)d * HW] = f2b(o[d] * r);
}

// ---------------- high-freq gate: p,v-hat -> res_h bf16. grid 1024, 64-px LDS tiles ------
__global__ __launch_bounds__(256) void k_resh(const bf16* __restrict__ p, const bf16* __restrict__ v,
                                              const float* __restrict__ Wa1, const float* __restrict__ ba1,
                                              const float* __restrict__ Wa2, const float* __restrict__ ba2,
                                              bf16* __restrict__ resh)
{
    __shared__ float ps[64 * 64];
    __shared__ float ss[64 * 64];
    int tid = threadIdx.x;
    int b = blockIdx.x >> 8, tile = blockIdx.x & 255;
    int px0 = tile * 64;
    const bf16* pb = p + (size_t)b * 64 * HW + px0;
    #pragma unroll
    for (int i = 0; i < 16; i++) {
        int c = i * 4 + (tid >> 6), px = tid & 63;
        ps[c * 64 + px] = b2f(pb[(size_t)c * HW + px]);
    }
    __syncthreads();
    int q = wuniform(tid >> 6);      // SGPR
    int px = tid & 63;
    float pr[64];
    #pragma unroll
    for (int c = 0; c < 64; c++) pr[c] = ps[c * 64 + px];
    #pragma unroll 1
    for (int o = 0; o < 16; o++) {
        int oc = q * 16 + o;
        const float* w = Wa1 + oc * 64;
        float s0 = 0.f, s1 = 0.f, s2 = 0.f, s3 = 0.f;
        #pragma unroll
        for (int c = 0; c < 64; c += 4) {
            s0 += w[c] * pr[c]; s1 += w[c + 1] * pr[c + 1];
            s2 += w[c + 2] * pr[c + 2]; s3 += w[c + 3] * pr[c + 3];
        }
        float a = ba1[oc] + ((s0 + s1) + (s2 + s3));
        ss[oc * 64 + px] = a / (1.f + __expf(-a));   // swish
    }
    __syncthreads();
    float sr[64];
    #pragma unroll
    for (int c = 0; c < 64; c++) sr[c] = ss[c * 64 + px];
    #pragma unroll 1
    for (int o = 0; o < 16; o++) {
        int oc = q * 16 + o;
        const float* w = Wa2 + oc * 64;
        float s0 = 0.f, s1 = 0.f, s2 = 0.f, s3 = 0.f;
        #pragma unroll
        for (int c = 0; c < 64; c += 4) {
            s0 += w[c] * sr[c]; s1 += w[c + 1] * sr[c + 1];
            s2 += w[c + 2] * sr[c + 2]; s3 += w[c + 3] * sr[c + 3];
        }
        float acc = ba2[oc] + ((s0 + s1) + (s2 + s3));
        float g = tanhf(acc * 0.25f);
        float vv = b2f(v[(size_t)(b * 64 + oc) * HW + px0 + px]);
        resh[(size_t)(b * 64 + oc) * HW + px0 + px] = f2b(g * vv);
    }
}

// ---------------- final proj: [res_h | res_l] -> out fp32. grid 1024, 64-px LDS tiles ----
__global__ __launch_bounds__(256) void k_proj(const bf16* __restrict__ resh, const bf16* __restrict__ qkvg,
                                              const float* __restrict__ Wproj, const float* __restrict__ bproj,
                                              float* __restrict__ out)
{
    __shared__ float cs[128 * 64];
    int tid = threadIdx.x;
    int b = blockIdx.x >> 8, tile = blockIdx.x & 255;
    int px0 = tile * 64;
    const bf16* rh = resh + (size_t)b * 64 * HW + px0;
    const bf16* rl = qkvg + (size_t)(b * 256 + 192) * HW + px0;
    #pragma unroll
    for (int i = 0; i < 16; i++) {
        int c = i * 4 + (tid >> 6), px = tid & 63;
        cs[c * 64 + px] = b2f(rh[(size_t)c * HW + px]);
        cs[(64 + c) * 64 + px] = b2f(rl[(size_t)c * HW + px]);
    }
    __syncthreads();
    int q = wuniform(tid >> 6);      // SGPR
    int px = tid & 63;
    float xr[128];
    #pragma unroll
    for (int c = 0; c < 128; c++) xr[c] = cs[c * 64 + px];
    float* outp = out + (size_t)(b * 128 + q * 32) * HW + px0 + px;
    const float* W = Wproj + q * 32 * 128;
    const float* bias = bproj + q * 32;
    #pragma unroll 1
    for (int og = 0; og < 8; og++) {
        int o = og * 4;
        float a0 = bias[o], a1 = bias[o + 1], a2 = bias[o + 2], a3 = bias[o + 3];
        const float* w0 = W + (o + 0) * 128;
        const float* w1 = W + (o + 1) * 128;
        const float* w2 = W + (o + 2) * 128;
        const float* w3 = W + (o + 3) * 128;
        #pragma unroll
        for (int c = 0; c < 128; c++) {
            float xv = xr[c];
            a0 += w0[c] * xv; a1 += w1[c] * xv; a2 += w2[c] * xv; a3 += w3[c] * xv;
        }
        outp[(size_t)(o + 0) * HW] = a0; outp[(size_t)(o + 1) * HW] = a1;
        outp[(size_t)(o + 2) * HW] = a2; outp[(size_t)(o + 3) * HW] = a3;
    }
}

extern "C" void kernel_launch(void* const* d_in, const int* in_sizes, int n_in,
                              void* d_out, int out_size, void* d_ws, size_t ws_size,
                              hipStream_t stream)
{
    (void)in_sizes; (void)n_in; (void)out_size; (void)ws_size;
    const float* x     = (const float*)d_in[0];
    const float* Wqkv  = (const float*)d_in[1];
    const float* bqkv  = (const float*)d_in[2];
    const float* Wdw   = (const float*)d_in[3];
    const float* bdw   = (const float*)d_in[4];
    const float* Wa1   = (const float*)d_in[5];
    const float* ba1   = (const float*)d_in[6];
    const float* Wa2   = (const float*)d_in[7];
    const float* ba2   = (const float*)d_in[8];
    const float* Wq    = (const float*)d_in[9];
    const float* bq    = (const float*)d_in[10];
    const float* Wkv   = (const float*)d_in[11];
    const float* bkv   = (const float*)d_in[12];
    const float* Wproj = (const float*)d_in[13];
    const float* bproj = (const float*)d_in[14];

    char* wsb = (char*)d_ws;
    float* xp   = (float*)(wsb + OFFB_XP);
    float* k2   = (float*)(wsb + OFFB_K2);
    float* v2   = (float*)(wsb + OFFB_V2);
    bf16*  qkvg = (bf16*)(wsb + OFFB_QKVG);
    bf16*  resh = (bf16*)(wsb + OFFB_RESH);
    bf16*  p    = (bf16*)d_out;                  // scratch in d_out, dead before k_proj
    bf16*  v    = (bf16*)d_out + 4194304;
    float* out  = (float*)d_out;

    k_pool<<<dim3(512), 256, 0, stream>>>(x, xp);
    k_kv<<<dim3(64), 256, 0, stream>>>(xp, Wkv, bkv, k2, v2);
    k_conv<<<dim3(1024), 256, 0, stream>>>(x, Wqkv, bqkv, Wq, bq, qkvg);
    k_dw<<<dim3(16384), 256, 0, stream>>>(qkvg, Wdw, bdw, p, v);
    k_attn<<<dim3(64, 4, 4), 256, 0, stream>>>(qkvg, k2, v2);       // res_l in-place over qg ch
    k_resh<<<dim3(1024), 256, 0, stream>>>(p, v, Wa1, ba1, Wa2, ba2, resh);
    k_proj<<<dim3(1024), 256, 0, stream>>>(resh, qkvg, Wproj, bproj, out);
}

// Round 6
// 359.188 us; speedup vs baseline: 2.1707x; 1.4145x over previous
//
#include <hip/hip_runtime.h>
#include <hip/hip_bf16.h>

typedef __hip_bfloat16 bf16;
typedef short short8v __attribute__((ext_vector_type(8)));
typedef short short4v __attribute__((ext_vector_type(4)));
typedef float floatx4 __attribute__((ext_vector_type(4)));

#define HW 16384

__device__ __forceinline__ float b2f(bf16 v) { return __bfloat162float(v); }
__device__ __forceinline__ bf16 f2b(float v) { return __float2bfloat16(v); }
__device__ __forceinline__ short f2bs(float v) { bf16 h = __float2bfloat16(v); return __builtin_bit_cast(short, h); }
__device__ __forceinline__ int wuniform(int v) { return __builtin_amdgcn_readfirstlane(v); }

// ---- ws byte offsets (total 41 MiB, proven safe) ----
#define OFFB_XP    0u
#define OFFB_K2    524288u
#define OFFB_V2    786432u
#define OFFB_QKVG  (1u << 20)         // bf16 (b,256,HW): 0-63 q, 64-127 k, 128-191 v, 192-255 qg->res_l
#define OFFB_RESH  (33u << 20)        // bf16 (b,64,HW)
// p / v-hat scratch in d_out [0,16MiB); d_out fully overwritten by k_proj.

// ---------------- 8x8 avgpool ----------------
__global__ __launch_bounds__(256) void k_pool(const float* __restrict__ x, float* __restrict__ xp)
{
    int idx = blockIdx.x * 256 + threadIdx.x;
    int j = idx & 15, i = (idx >> 4) & 15, bc = idx >> 8;
    const float* src = x + (size_t)bc * HW + (i * 8) * 128 + j * 8;
    float s = 0.f;
    #pragma unroll
    for (int u = 0; u < 8; u++) {
        #pragma unroll
        for (int t = 0; t < 8; t++) s += src[u * 128 + t];
    }
    xp[bc * 256 + i * 16 + j] = s * (1.f / 64.f);
}

// ---------------- kv conv: xp -> k2/v2 fp32 (b,h,m,d) ----------------
__global__ __launch_bounds__(256) void k_kv(const float* __restrict__ xp,
                                            const float* __restrict__ Wkv, const float* __restrict__ bkv,
                                            float* __restrict__ k2, float* __restrict__ v2)
{
    int og = blockIdx.x & 15, b = blockIdx.x >> 4;
    int m = threadIdx.x;
    float xr[128];
    #pragma unroll
    for (int c = 0; c < 128; c++) xr[c] = xp[(b * 128 + c) * 256 + m];
    #pragma unroll 1
    for (int t = 0; t < 8; t++) {
        int o = og * 8 + t;
        const float* w = Wkv + o * 128;
        float s0 = 0.f, s1 = 0.f, s2 = 0.f, s3 = 0.f;
        #pragma unroll
        for (int c = 0; c < 128; c += 4) {
            s0 += w[c] * xr[c]; s1 += w[c + 1] * xr[c + 1];
            s2 += w[c + 2] * xr[c + 2]; s3 += w[c + 3] * xr[c + 3];
        }
        float a = bkv[o] + ((s0 + s1) + (s2 + s3));
        int sb = o >> 6, r = o & 63, gh = r >> 4, dh = r & 15;
        float* dst = sb == 0 ? k2 : v2;
        dst[((b * 4 + gh) * 256 + m) * 16 + dh] = a;
    }
}

// ---------------- MFMA conv1x1: x -> qkvg bf16. grid (128 px-tiles, 2 m-blocks, 4 b) -----
// C[256oc x 16384px] = Wcat[256x128] * X[128x16384] per batch, bf16 MFMA 16x16x32.
__global__ __launch_bounds__(256) void k_conv(const float* __restrict__ x,
                                              const float* __restrict__ Wqkv, const float* __restrict__ bqkv,
                                              const float* __restrict__ Wq,  const float* __restrict__ bq,
                                              bf16* __restrict__ qkvg)
{
    __shared__ short a_s[128 * 128];          // A[oc][k] bf16
    __shared__ short b_s[128 * 128];          // B packed [k>>3][px][k&7] bf16
    __shared__ float bias_s[128];
    int t = threadIdx.x;
    int b = blockIdx.z, my = blockIdx.y;
    int px0 = blockIdx.x * 128;

    if (t < 128) {
        int oc = my * 128 + t;
        bias_s[t] = (oc < 192) ? bqkv[oc] : bq[oc - 192];
    }
    #pragma unroll
    for (int i = 0; i < 16; i++) {            // stage A: W fp32 -> bf16
        int idx = i * 1024 + t * 4;
        int row = idx >> 7, col = idx & 127;
        int oc = my * 128 + row;
        const float* src = (oc < 192) ? (Wqkv + oc * 128 + col) : (Wq + (oc - 192) * 128 + col);
        floatx4 wv = *(const floatx4*)src;
        short4v pk;
        pk[0] = f2bs(wv[0]); pk[1] = f2bs(wv[1]); pk[2] = f2bs(wv[2]); pk[3] = f2bs(wv[3]);
        *(short4v*)&a_s[row * 128 + col] = pk;
    }
    #pragma unroll
    for (int i = 0; i < 16; i++) {            // stage B: x fp32 -> packed bf16
        int idx = i * 1024 + t * 4;
        int c = idx >> 7, px = idx & 127;
        floatx4 xv = *(const floatx4*)(x + ((size_t)b * 128 + c) * HW + px0 + px);
        #pragma unroll
        for (int e = 0; e < 4; e++)
            b_s[((c >> 3) * 128 + px + e) * 8 + (c & 7)] = f2bs(xv[e]);
    }
    __syncthreads();

    int wave = wuniform(t >> 6);
    int lane = t & 63;
    int quad = lane >> 4, l16 = lane & 15;
    floatx4 acc[2][8] = {};
    #pragma unroll
    for (int kk = 0; kk < 4; kk++) {
        short8v a0 = *(const short8v*)&a_s[(wave * 32 + l16) * 128 + kk * 32 + quad * 8];
        short8v a1 = *(const short8v*)&a_s[(wave * 32 + 16 + l16) * 128 + kk * 32 + quad * 8];
        #pragma unroll
        for (int nt = 0; nt < 8; nt++) {
            short8v bv = *(const short8v*)&b_s[((kk * 4 + quad) * 128 + nt * 16 + l16) * 8];
            acc[0][nt] = __builtin_amdgcn_mfma_f32_16x16x32_bf16(a0, bv, acc[0][nt], 0, 0, 0);
            acc[1][nt] = __builtin_amdgcn_mfma_f32_16x16x32_bf16(a1, bv, acc[1][nt], 0, 0, 0);
        }
    }
    #pragma unroll
    for (int m = 0; m < 2; m++) {
        int rowb = wave * 32 + m * 16 + quad * 4;
        #pragma unroll
        for (int nt = 0; nt < 8; nt++) {
            int px = px0 + nt * 16 + l16;
            #pragma unroll
            for (int r = 0; r < 4; r++) {
                int row = rowb + r;
                float val = acc[m][nt][r] + bias_s[row];
                qkvg[((size_t)b * 256 + my * 128 + row) * HW + px] = f2b(val);
            }
        }
    }
}

// ---------------- depthwise 3x3 + q*k ----------------
__global__ __launch_bounds__(256) void k_dw(const bf16* __restrict__ qkvg,
                                            const float* __restrict__ Wdw, const float* __restrict__ bdw,
                                            bf16* __restrict__ p, bf16* __restrict__ v)
{
    int nblk = blockIdx.x & 63;
    int bc = blockIdx.x >> 6;
    int c = bc & 63, b = bc >> 6;
    int n = nblk * 256 + threadIdx.x;
    int i = n >> 7, j = n & 127;
    const bf16* in0 = qkvg + (size_t)(b * 256 + c) * HW;
    const bf16* in1 = qkvg + (size_t)(b * 256 + 64 + c) * HW;
    const bf16* in2 = qkvg + (size_t)(b * 256 + 128 + c) * HW;
    float aq = bdw[c], ak = bdw[64 + c], av = bdw[128 + c];
    #pragma unroll
    for (int dy = 0; dy < 3; dy++) {
        int ii = i + dy - 1;
        bool iv = (unsigned)ii < 128u;
        #pragma unroll
        for (int dx = 0; dx < 3; dx++) {
            int jj = j + dx - 1;
            bool ok = iv && ((unsigned)jj < 128u);
            int off = ii * 128 + jj;
            float q0 = ok ? b2f(in0[off]) : 0.f;
            float k0 = ok ? b2f(in1[off]) : 0.f;
            float v0 = ok ? b2f(in2[off]) : 0.f;
            int tt = dy * 3 + dx;
            aq += Wdw[c * 9 + tt] * q0;
            ak += Wdw[(64 + c) * 9 + tt] * k0;
            av += Wdw[(128 + c) * 9 + tt] * v0;
        }
    }
    p[(size_t)(b * 64 + c) * HW + n] = f2b(aq * ak);
    v[(size_t)(b * 64 + c) * HW + n] = f2b(av);
}

// ---------------- low-freq attention, LDS-staged K/V. grid (64,4,4) ----------------
__global__ __launch_bounds__(256) void k_attn(bf16* __restrict__ qkvg, const float* __restrict__ k2,
                                              const float* __restrict__ v2)
{
    __shared__ float4 kf[1024];
    __shared__ float4 vf[1024];
    int tid = threadIdx.x;
    int h = blockIdx.y, b = blockIdx.z;
    const float4* kb = (const float4*)(k2 + (size_t)(b * 4 + h) * 4096);
    const float4* vb = (const float4*)(v2 + (size_t)(b * 4 + h) * 4096);
    #pragma unroll
    for (int i = 0; i < 4; i++) {
        kf[i * 256 + tid] = kb[i * 256 + tid];
        vf[i * 256 + tid] = vb[i * 256 + tid];
    }
    __syncthreads();
    int n = blockIdx.x * 256 + tid;
    bf16* qp = qkvg + (size_t)(b * 256 + 192 + h * 16) * HW + n;
    float qv[16];
    #pragma unroll
    for (int d = 0; d < 16; d++) qv[d] = b2f(qp[(size_t)d * HW]) * 0.25f;
    float o[16];
    #pragma unroll
    for (int d = 0; d < 16; d++) o[d] = 0.f;
    float den = 0.f;
    #pragma unroll 2
    for (int m = 0; m < 256; m++) {
        float4 ka = kf[m * 4 + 0], kb1 = kf[m * 4 + 1], kc = kf[m * 4 + 2], kd = kf[m * 4 + 3];
        float s0 = qv[0] * ka.x + qv[1] * ka.y + qv[2] * ka.z + qv[3] * ka.w;
        float s1 = qv[4] * kb1.x + qv[5] * kb1.y + qv[6] * kb1.z + qv[7] * kb1.w;
        float s2 = qv[8] * kc.x + qv[9] * kc.y + qv[10] * kc.z + qv[11] * kc.w;
        float s3 = qv[12] * kd.x + qv[13] * kd.y + qv[14] * kd.z + qv[15] * kd.w;
        float s = (s0 + s1) + (s2 + s3);
        s = fminf(fmaxf(s, -60.f), 60.f);
        float e = __expf(s);
        den += e;
        float4 va = vf[m * 4 + 0], vb1 = vf[m * 4 + 1], vc = vf[m * 4 + 2], vd = vf[m * 4 + 3];
        o[0] += e * va.x;  o[1] += e * va.y;  o[2] += e * va.z;  o[3] += e * va.w;
        o[4] += e * vb1.x; o[5] += e * vb1.y; o[6] += e * vb1.z; o[7] += e * vb1.w;
        o[8] += e * vc.x;  o[9] += e * vc.y;  o[10] += e * vc.z; o[11] += e * vc.w;
        o[12] += e * vd.x; o[13] += e * vd.y; o[14] += e * vd.z; o[15] += e * vd.w;
    }
    float r = 1.f / den;
    #pragma unroll
    for (int d = 0; d < 16; d++) qp[(size_t)d * HW] = f2b(o[d] * r);
}

// ---------------- high-freq gate: p,v-hat -> res_h bf16. grid 1024, 64-px LDS tiles ------
__global__ __launch_bounds__(256) void k_resh(const bf16* __restrict__ p, const bf16* __restrict__ v,
                                              const float* __restrict__ Wa1, const float* __restrict__ ba1,
                                              const float* __restrict__ Wa2, const float* __restrict__ ba2,
                                              bf16* __restrict__ resh)
{
    __shared__ float ps[64 * 64];
    __shared__ float ss[64 * 64];
    int tid = threadIdx.x;
    int b = blockIdx.x >> 8, tile = blockIdx.x & 255;
    int px0 = tile * 64;
    const bf16* pb = p + (size_t)b * 64 * HW + px0;
    #pragma unroll
    for (int i = 0; i < 16; i++) {
        int c = i * 4 + (tid >> 6), px = tid & 63;
        ps[c * 64 + px] = b2f(pb[(size_t)c * HW + px]);
    }
    __syncthreads();
    int q = wuniform(tid >> 6);
    int px = tid & 63;
    float pr[64];
    #pragma unroll
    for (int c = 0; c < 64; c++) pr[c] = ps[c * 64 + px];
    #pragma unroll 1
    for (int o = 0; o < 16; o++) {
        int oc = q * 16 + o;
        const float* w = Wa1 + oc * 64;
        float s0 = 0.f, s1 = 0.f, s2 = 0.f, s3 = 0.f;
        #pragma unroll
        for (int c = 0; c < 64; c += 4) {
            s0 += w[c] * pr[c]; s1 += w[c + 1] * pr[c + 1];
            s2 += w[c + 2] * pr[c + 2]; s3 += w[c + 3] * pr[c + 3];
        }
        float a = ba1[oc] + ((s0 + s1) + (s2 + s3));
        ss[oc * 64 + px] = a / (1.f + __expf(-a));
    }
    __syncthreads();
    float sr[64];
    #pragma unroll
    for (int c = 0; c < 64; c++) sr[c] = ss[c * 64 + px];
    #pragma unroll 1
    for (int o = 0; o < 16; o++) {
        int oc = q * 16 + o;
        const float* w = Wa2 + oc * 64;
        float s0 = 0.f, s1 = 0.f, s2 = 0.f, s3 = 0.f;
        #pragma unroll
        for (int c = 0; c < 64; c += 4) {
            s0 += w[c] * sr[c]; s1 += w[c + 1] * sr[c + 1];
            s2 += w[c + 2] * sr[c + 2]; s3 += w[c + 3] * sr[c + 3];
        }
        float acc = ba2[oc] + ((s0 + s1) + (s2 + s3));
        float g = tanhf(acc * 0.25f);
        float vv = b2f(v[(size_t)(b * 64 + oc) * HW + px0 + px]);
        resh[(size_t)(b * 64 + oc) * HW + px0 + px] = f2b(g * vv);
    }
}

// ---------------- MFMA final proj: [res_h|res_l] -> out fp32. grid (128 px-tiles, 4 b) ---
__global__ __launch_bounds__(256) void k_proj(const bf16* __restrict__ resh, const bf16* __restrict__ qkvg,
                                              const float* __restrict__ Wproj, const float* __restrict__ bproj,
                                              float* __restrict__ out)
{
    __shared__ short a_s[128 * 128];
    __shared__ short b_s[128 * 128];
    __shared__ float bias_s[128];
    int t = threadIdx.x;
    int b = blockIdx.y;
    int px0 = blockIdx.x * 128;
    const bf16* resl = qkvg + (size_t)(b * 256 + 192) * HW;

    if (t < 128) bias_s[t] = bproj[t];
    #pragma unroll
    for (int i = 0; i < 16; i++) {            // stage A: Wproj fp32 -> bf16
        int idx = i * 1024 + t * 4;
        int row = idx >> 7, col = idx & 127;
        floatx4 wv = *(const floatx4*)(Wproj + row * 128 + col);
        short4v pk;
        pk[0] = f2bs(wv[0]); pk[1] = f2bs(wv[1]); pk[2] = f2bs(wv[2]); pk[3] = f2bs(wv[3]);
        *(short4v*)&a_s[row * 128 + col] = pk;
    }
    #pragma unroll
    for (int i = 0; i < 16; i++) {            // stage B: bf16 repack
        int idx = i * 1024 + t * 4;
        int c = idx >> 7, px = idx & 127;
        const short* src = (c < 64) ? (const short*)(resh + ((size_t)b * 64 + c) * HW + px0 + px)
                                    : (const short*)(resl + (size_t)(c - 64) * HW + px0 + px);
        short4v xv = *(const short4v*)src;
        #pragma unroll
        for (int e = 0; e < 4; e++)
            b_s[((c >> 3) * 128 + px + e) * 8 + (c & 7)] = xv[e];
    }
    __syncthreads();

    int wave = wuniform(t >> 6);
    int lane = t & 63;
    int quad = lane >> 4, l16 = lane & 15;
    floatx4 acc[2][8] = {};
    #pragma unroll
    for (int kk = 0; kk < 4; kk++) {
        short8v a0 = *(const short8v*)&a_s[(wave * 32 + l16) * 128 + kk * 32 + quad * 8];
        short8v a1 = *(const short8v*)&a_s[(wave * 32 + 16 + l16) * 128 + kk * 32 + quad * 8];
        #pragma unroll
        for (int nt = 0; nt < 8; nt++) {
            short8v bv = *(const short8v*)&b_s[((kk * 4 + quad) * 128 + nt * 16 + l16) * 8];
            acc[0][nt] = __builtin_amdgcn_mfma_f32_16x16x32_bf16(a0, bv, acc[0][nt], 0, 0, 0);
            acc[1][nt] = __builtin_amdgcn_mfma_f32_16x16x32_bf16(a1, bv, acc[1][nt], 0, 0, 0);
        }
    }
    #pragma unroll
    for (int m = 0; m < 2; m++) {
        int rowb = wave * 32 + m * 16 + quad * 4;
        #pragma unroll
        for (int nt = 0; nt < 8; nt++) {
            int px = px0 + nt * 16 + l16;
            #pragma unroll
            for (int r = 0; r < 4; r++) {
                int row = rowb + r;
                out[((size_t)b * 128 + row) * HW + px] = acc[m][nt][r] + bias_s[row];
            }
        }
    }
}

extern "C" void kernel_launch(void* const* d_in, const int* in_sizes, int n_in,
                              void* d_out, int out_size, void* d_ws, size_t ws_size,
                              hipStream_t stream)
{
    (void)in_sizes; (void)n_in; (void)out_size; (void)ws_size;
    const float* x     = (const float*)d_in[0];
    const float* Wqkv  = (const float*)d_in[1];
    const float* bqkv  = (const float*)d_in[2];
    const float* Wdw   = (const float*)d_in[3];
    const float* bdw   = (const float*)d_in[4];
    const float* Wa1   = (const float*)d_in[5];
    const float* ba1   = (const float*)d_in[6];
    const float* Wa2   = (const float*)d_in[7];
    const float* ba2   = (const float*)d_in[8];
    const float* Wq    = (const float*)d_in[9];
    const float* bq    = (const float*)d_in[10];
    const float* Wkv   = (const float*)d_in[11];
    const float* bkv   = (const float*)d_in[12];
    const float* Wproj = (const float*)d_in[13];
    const float* bproj = (const float*)d_in[14];

    char* wsb = (char*)d_ws;
    float* xp   = (float*)(wsb + OFFB_XP);
    float* k2   = (float*)(wsb + OFFB_K2);
    float* v2   = (float*)(wsb + OFFB_V2);
    bf16*  qkvg = (bf16*)(wsb + OFFB_QKVG);
    bf16*  resh = (bf16*)(wsb + OFFB_RESH);
    bf16*  p    = (bf16*)d_out;                  // scratch in d_out, dead before k_proj
    bf16*  v    = (bf16*)d_out + 4194304;
    float* out  = (float*)d_out;

    k_pool<<<dim3(512), 256, 0, stream>>>(x, xp);
    k_kv<<<dim3(64), 256, 0, stream>>>(xp, Wkv, bkv, k2, v2);
    k_conv<<<dim3(128, 2, 4), 256, 0, stream>>>(x, Wqkv, bqkv, Wq, bq, qkvg);
    k_dw<<<dim3(16384), 256, 0, stream>>>(qkvg, Wdw, bdw, p, v);
    k_attn<<<dim3(64, 4, 4), 256, 0, stream>>>(qkvg, k2, v2);       // res_l in-place over qg ch
    k_resh<<<dim3(1024), 256, 0, stream>>>(p, v, Wa1, ba1, Wa2, ba2, resh);
    k_proj<<<dim3(128, 4), 256, 0, stream>>>(resh, qkvg, Wproj, bproj, out);
}

// Round 7
// 311.629 us; speedup vs baseline: 2.5020x; 1.1526x over previous
//
#include <hip/hip_runtime.h>
#include <hip/hip_bf16.h>

typedef __hip_bfloat16 bf16;
typedef short short8v __attribute__((ext_vector_type(8)));
typedef short short4v __attribute__((ext_vector_type(4)));
typedef float floatx4 __attribute__((ext_vector_type(4)));

#define HW 16384

__device__ __forceinline__ float b2f(bf16 v) { return __bfloat162float(v); }
__device__ __forceinline__ bf16 f2b(float v) { return __float2bfloat16(v); }
__device__ __forceinline__ short f2bs(float v) { bf16 h = __float2bfloat16(v); return __builtin_bit_cast(short, h); }
__device__ __forceinline__ float bs2f(short s) { return b2f(__builtin_bit_cast(bf16, s)); }
__device__ __forceinline__ int wuniform(int v) { return __builtin_amdgcn_readfirstlane(v); }

// ---- ws byte offsets (total 41 MiB, proven safe) ----
#define OFFB_XP    0u
#define OFFB_K2    524288u
#define OFFB_V2    786432u
#define OFFB_QKVG  (1u << 20)         // bf16 (b,256,HW): 0-63 q, 64-127 k, 128-191 v, 192-255 qg->res_l
#define OFFB_RESH  (33u << 20)        // bf16 (b,64,HW)
// p / v-hat scratch in d_out [0,16MiB); d_out fully overwritten by k_proj.

// ---------------- 8x8 avgpool ----------------
__global__ __launch_bounds__(256) void k_pool(const float* __restrict__ x, float* __restrict__ xp)
{
    int idx = blockIdx.x * 256 + threadIdx.x;
    int j = idx & 15, i = (idx >> 4) & 15, bc = idx >> 8;
    const float* src = x + (size_t)bc * HW + (i * 8) * 128 + j * 8;
    float s = 0.f;
    #pragma unroll
    for (int u = 0; u < 8; u++) {
        #pragma unroll
        for (int t = 0; t < 8; t++) s += src[u * 128 + t];
    }
    xp[bc * 256 + i * 16 + j] = s * (1.f / 64.f);
}

// ---------------- kv conv: xp -> k2/v2 fp32 (b,h,m,d) ----------------
__global__ __launch_bounds__(256) void k_kv(const float* __restrict__ xp,
                                            const float* __restrict__ Wkv, const float* __restrict__ bkv,
                                            float* __restrict__ k2, float* __restrict__ v2)
{
    int og = blockIdx.x & 15, b = blockIdx.x >> 4;
    int m = threadIdx.x;
    float xr[128];
    #pragma unroll
    for (int c = 0; c < 128; c++) xr[c] = xp[(b * 128 + c) * 256 + m];
    #pragma unroll 1
    for (int t = 0; t < 8; t++) {
        int o = og * 8 + t;
        const float* w = Wkv + o * 128;
        float s0 = 0.f, s1 = 0.f, s2 = 0.f, s3 = 0.f;
        #pragma unroll
        for (int c = 0; c < 128; c += 4) {
            s0 += w[c] * xr[c]; s1 += w[c + 1] * xr[c + 1];
            s2 += w[c + 2] * xr[c + 2]; s3 += w[c + 3] * xr[c + 3];
        }
        float a = bkv[o] + ((s0 + s1) + (s2 + s3));
        int sb = o >> 6, r = o & 63, gh = r >> 4, dh = r & 15;
        float* dst = sb == 0 ? k2 : v2;
        dst[((b * 4 + gh) * 256 + m) * 16 + dh] = a;
    }
}

// ---------------- MFMA conv1x1: x -> qkvg bf16. grid (128 px-tiles, 2 m-blocks, 4 b) -----
__global__ __launch_bounds__(256) void k_conv(const float* __restrict__ x,
                                              const float* __restrict__ Wqkv, const float* __restrict__ bqkv,
                                              const float* __restrict__ Wq,  const float* __restrict__ bq,
                                              bf16* __restrict__ qkvg)
{
    __shared__ short a_s[128 * 128];          // A[oc][k] bf16
    __shared__ short b_s[128 * 128];          // B packed [k>>3][px][k&7] bf16
    __shared__ float bias_s[128];
    int t = threadIdx.x;
    int b = blockIdx.z, my = blockIdx.y;
    int px0 = blockIdx.x * 128;

    if (t < 128) {
        int oc = my * 128 + t;
        bias_s[t] = (oc < 192) ? bqkv[oc] : bq[oc - 192];
    }
    #pragma unroll
    for (int i = 0; i < 16; i++) {            // stage A: W fp32 -> bf16
        int idx = i * 1024 + t * 4;
        int row = idx >> 7, col = idx & 127;
        int oc = my * 128 + row;
        const float* src = (oc < 192) ? (Wqkv + oc * 128 + col) : (Wq + (oc - 192) * 128 + col);
        floatx4 wv = *(const floatx4*)src;
        short4v pk;
        pk[0] = f2bs(wv[0]); pk[1] = f2bs(wv[1]); pk[2] = f2bs(wv[2]); pk[3] = f2bs(wv[3]);
        *(short4v*)&a_s[row * 128 + col] = pk;
    }
    #pragma unroll
    for (int i = 0; i < 16; i++) {            // stage B: x fp32 -> packed bf16
        int idx = i * 1024 + t * 4;
        int c = idx >> 7, px = idx & 127;
        floatx4 xv = *(const floatx4*)(x + ((size_t)b * 128 + c) * HW + px0 + px);
        #pragma unroll
        for (int e = 0; e < 4; e++)
            b_s[((c >> 3) * 128 + px + e) * 8 + (c & 7)] = f2bs(xv[e]);
    }
    __syncthreads();

    int wave = wuniform(t >> 6);
    int lane = t & 63;
    int quad = lane >> 4, l16 = lane & 15;
    floatx4 acc[2][8] = {};
    #pragma unroll
    for (int kk = 0; kk < 4; kk++) {
        short8v a0 = *(const short8v*)&a_s[(wave * 32 + l16) * 128 + kk * 32 + quad * 8];
        short8v a1 = *(const short8v*)&a_s[(wave * 32 + 16 + l16) * 128 + kk * 32 + quad * 8];
        #pragma unroll
        for (int nt = 0; nt < 8; nt++) {
            short8v bv = *(const short8v*)&b_s[((kk * 4 + quad) * 128 + nt * 16 + l16) * 8];
            acc[0][nt] = __builtin_amdgcn_mfma_f32_16x16x32_bf16(a0, bv, acc[0][nt], 0, 0, 0);
            acc[1][nt] = __builtin_amdgcn_mfma_f32_16x16x32_bf16(a1, bv, acc[1][nt], 0, 0, 0);
        }
    }
    #pragma unroll
    for (int m = 0; m < 2; m++) {
        int rowb = wave * 32 + m * 16 + quad * 4;
        #pragma unroll
        for (int nt = 0; nt < 8; nt++) {
            int px = px0 + nt * 16 + l16;
            #pragma unroll
            for (int r = 0; r < 4; r++) {
                int row = rowb + r;
                float val = acc[m][nt][r] + bias_s[row];
                qkvg[((size_t)b * 256 + my * 128 + row) * HW + px] = f2b(val);
            }
        }
    }
}

// ---------------- depthwise 3x3 + q*k ----------------
__global__ __launch_bounds__(256) void k_dw(const bf16* __restrict__ qkvg,
                                            const float* __restrict__ Wdw, const float* __restrict__ bdw,
                                            bf16* __restrict__ p, bf16* __restrict__ v)
{
    int nblk = blockIdx.x & 63;
    int bc = blockIdx.x >> 6;
    int c = bc & 63, b = bc >> 6;
    int n = nblk * 256 + threadIdx.x;
    int i = n >> 7, j = n & 127;
    const bf16* in0 = qkvg + (size_t)(b * 256 + c) * HW;
    const bf16* in1 = qkvg + (size_t)(b * 256 + 64 + c) * HW;
    const bf16* in2 = qkvg + (size_t)(b * 256 + 128 + c) * HW;
    float aq = bdw[c], ak = bdw[64 + c], av = bdw[128 + c];
    #pragma unroll
    for (int dy = 0; dy < 3; dy++) {
        int ii = i + dy - 1;
        bool iv = (unsigned)ii < 128u;
        #pragma unroll
        for (int dx = 0; dx < 3; dx++) {
            int jj = j + dx - 1;
            bool ok = iv && ((unsigned)jj < 128u);
            int off = ii * 128 + jj;
            float q0 = ok ? b2f(in0[off]) : 0.f;
            float k0 = ok ? b2f(in1[off]) : 0.f;
            float v0 = ok ? b2f(in2[off]) : 0.f;
            int tt = dy * 3 + dx;
            aq += Wdw[c * 9 + tt] * q0;
            ak += Wdw[(64 + c) * 9 + tt] * k0;
            av += Wdw[(128 + c) * 9 + tt] * v0;
        }
    }
    p[(size_t)(b * 64 + c) * HW + n] = f2b(aq * ak);
    v[(size_t)(b * 64 + c) * HW + n] = f2b(av);
}

// ---------------- MFMA low-freq attention. grid (64 px-blocks, 4 h, 4 b) ----------------
// Per block: 256 px, one (b,h). S^T = K*Q^T (MFMA, K-dim=16 padded to 32), softmax in regs,
// O^T = V^T*P^T (MFMA over m=256). All operands staged fragment-ordered in LDS.
__global__ __launch_bounds__(256) void k_attn(bf16* __restrict__ qkvg, const float* __restrict__ k2,
                                              const float* __restrict__ v2)
{
    __shared__ short kt[16 * 64 * 8];   // 16 KB  A-frags GEMM1: [mtile][lane][8]
    __shared__ short vt[8 * 64 * 8];    //  8 KB  A-frags GEMM2: [mblock][lane][8]
    __shared__ short un[32 * 64 * 8];   // 32 KB  union: qt B-frags [pxtile][lane][8] (first 16KB),
                                        //         then pt B-frags [wave*8+mblock][lane][8]
    int t = threadIdx.x;
    int h = blockIdx.y, b = blockIdx.z;
    int px0b = blockIdx.x * 256;
    const float* K = k2 + (size_t)(b * 4 + h) * 4096;
    const float* V = v2 + (size_t)(b * 4 + h) * 4096;
    bf16* Qbase = qkvg + (size_t)(b * 256 + 192 + h * 16) * HW + px0b;

    {   // stage kt: thread t = key row m; pad d 16..31 with zeros
        int mt = t >> 4, l16k = t & 15;
        float4 k0 = *(const float4*)(K + t * 16);
        float4 k1 = *(const float4*)(K + t * 16 + 4);
        float4 kx2 = *(const float4*)(K + t * 16 + 8);
        float4 k3 = *(const float4*)(K + t * 16 + 12);
        short8v lo, hi, zz = {};
        lo[0] = f2bs(k0.x); lo[1] = f2bs(k0.y); lo[2] = f2bs(k0.z); lo[3] = f2bs(k0.w);
        lo[4] = f2bs(k1.x); lo[5] = f2bs(k1.y); lo[6] = f2bs(k1.z); lo[7] = f2bs(k1.w);
        hi[0] = f2bs(kx2.x); hi[1] = f2bs(kx2.y); hi[2] = f2bs(kx2.z); hi[3] = f2bs(kx2.w);
        hi[4] = f2bs(k3.x); hi[5] = f2bs(k3.y); hi[6] = f2bs(k3.z); hi[7] = f2bs(k3.w);
        *(short8v*)&kt[(mt * 64 + l16k) * 8] = lo;
        *(short8v*)&kt[(mt * 64 + 16 + l16k) * 8] = hi;
        *(short8v*)&kt[(mt * 64 + 32 + l16k) * 8] = zz;
        *(short8v*)&kt[(mt * 64 + 48 + l16k) * 8] = zz;
    }
    #pragma unroll
    for (int u = 0; u < 2; u++) {   // stage vt: A-frag [d=lane&15][k=m_within=quad*8+i]
        int f = t * 2 + u;
        int mb = f >> 6, lane = f & 63, quad = lane >> 4, d = lane & 15;
        short8v pk;
        #pragma unroll
        for (int i = 0; i < 8; i++) pk[i] = f2bs(V[(mb * 32 + quad * 8 + i) * 16 + d]);
        *(short8v*)&vt[f * 8] = pk;
    }
    #pragma unroll
    for (int u = 0; u < 4; u++) {   // stage qt: B-frag [k=d][col=px], Q scaled x0.25, pad zeros
        int f = t * 4 + u;
        int pxt = f >> 6, lane = f & 63, quad = lane >> 4, l16 = lane & 15;
        int px = pxt * 16 + l16;
        short8v pk = {};
        if (quad < 2) {
            #pragma unroll
            for (int i = 0; i < 8; i++)
                pk[i] = f2bs(b2f(Qbase[(size_t)(quad * 8 + i) * HW + px]) * 0.25f);
        }
        *(short8v*)&un[f * 8] = pk;
    }
    __syncthreads();

    int wave = wuniform(t >> 6);
    int lane = t & 63;
    int quad = lane >> 4, l16 = lane & 15;
    short8v qf[4];
    #pragma unroll
    for (int u = 0; u < 4; u++)
        qf[u] = *(const short8v*)&un[((wave * 4 + u) * 64 + lane) * 8];
    __syncthreads();   // all qt reads done before un is reused as pt

    #pragma unroll 1
    for (int u = 0; u < 4; u++) {
        int pxt = wave * 4 + u;
        floatx4 sc[16];
        #pragma unroll
        for (int mt = 0; mt < 16; mt++) {
            short8v kf = *(const short8v*)&kt[(mt * 64 + lane) * 8];
            sc[mt] = __builtin_amdgcn_mfma_f32_16x16x32_bf16(kf, qf[u], (floatx4){0.f, 0.f, 0.f, 0.f}, 0, 0, 0);
        }
        float den = 0.f;
        #pragma unroll
        for (int mt = 0; mt < 16; mt++) {
            short4v pk;
            #pragma unroll
            for (int r = 0; r < 4; r++) {
                float s = fminf(fmaxf(sc[mt][r], -60.f), 60.f);
                short pb = f2bs(__expf(s));
                pk[r] = pb;
                den += bs2f(pb);
            }
            // C-layout (m = mt*16 + quad*4 + r, px = l16) -> B-frag position
            int mwin = (mt & 1) * 16 + quad * 4;
            int lane_d = (mwin >> 3) * 16 + l16;
            *(short4v*)&un[((wave * 8 + (mt >> 1)) * 64 + lane_d) * 8 + (mwin & 7)] = pk;
        }
        den += __shfl_xor(den, 16, 64);
        den += __shfl_xor(den, 32, 64);
        float rden = 1.f / den;
        floatx4 oa = {};
        #pragma unroll
        for (int mb = 0; mb < 8; mb++) {
            short8v vf = *(const short8v*)&vt[(mb * 64 + lane) * 8];
            short8v pf = *(const short8v*)&un[((wave * 8 + mb) * 64 + lane) * 8];
            oa = __builtin_amdgcn_mfma_f32_16x16x32_bf16(vf, pf, oa, 0, 0, 0);
        }
        #pragma unroll
        for (int r = 0; r < 4; r++)
            Qbase[(size_t)(quad * 4 + r) * HW + pxt * 16 + l16] = f2b(oa[r] * rden);
    }
}

// ---------------- high-freq gate: p,v-hat -> res_h bf16. grid 1024, 64-px LDS tiles ------
__global__ __launch_bounds__(256) void k_resh(const bf16* __restrict__ p, const bf16* __restrict__ v,
                                              const float* __restrict__ Wa1, const float* __restrict__ ba1,
                                              const float* __restrict__ Wa2, const float* __restrict__ ba2,
                                              bf16* __restrict__ resh)
{
    __shared__ float ps[64 * 64];
    __shared__ float ss[64 * 64];
    int tid = threadIdx.x;
    int b = blockIdx.x >> 8, tile = blockIdx.x & 255;
    int px0 = tile * 64;
    const bf16* pb = p + (size_t)b * 64 * HW + px0;
    #pragma unroll
    for (int i = 0; i < 16; i++) {
        int c = i * 4 + (tid >> 6), px = tid & 63;
        ps[c * 64 + px] = b2f(pb[(size_t)c * HW + px]);
    }
    __syncthreads();
    int q = wuniform(tid >> 6);
    int px = tid & 63;
    float pr[64];
    #pragma unroll
    for (int c = 0; c < 64; c++) pr[c] = ps[c * 64 + px];
    #pragma unroll 1
    for (int o = 0; o < 16; o++) {
        int oc = q * 16 + o;
        const float* w = Wa1 + oc * 64;
        float s0 = 0.f, s1 = 0.f, s2 = 0.f, s3 = 0.f;
        #pragma unroll
        for (int c = 0; c < 64; c += 4) {
            s0 += w[c] * pr[c]; s1 += w[c + 1] * pr[c + 1];
            s2 += w[c + 2] * pr[c + 2]; s3 += w[c + 3] * pr[c + 3];
        }
        float a = ba1[oc] + ((s0 + s1) + (s2 + s3));
        ss[oc * 64 + px] = a / (1.f + __expf(-a));
    }
    __syncthreads();
    float sr[64];
    #pragma unroll
    for (int c = 0; c < 64; c++) sr[c] = ss[c * 64 + px];
    #pragma unroll 1
    for (int o = 0; o < 16; o++) {
        int oc = q * 16 + o;
        const float* w = Wa2 + oc * 64;
        float s0 = 0.f, s1 = 0.f, s2 = 0.f, s3 = 0.f;
        #pragma unroll
        for (int c = 0; c < 64; c += 4) {
            s0 += w[c] * sr[c]; s1 += w[c + 1] * sr[c + 1];
            s2 += w[c + 2] * sr[c + 2]; s3 += w[c + 3] * sr[c + 3];
        }
        float acc = ba2[oc] + ((s0 + s1) + (s2 + s3));
        float g = tanhf(acc * 0.25f);
        float vv = b2f(v[(size_t)(b * 64 + oc) * HW + px0 + px]);
        resh[(size_t)(b * 64 + oc) * HW + px0 + px] = f2b(g * vv);
    }
}

// ---------------- MFMA final proj: [res_h|res_l] -> out fp32. grid (128 px-tiles, 4 b) ---
__global__ __launch_bounds__(256) void k_proj(const bf16* __restrict__ resh, const bf16* __restrict__ qkvg,
                                              const float* __restrict__ Wproj, const float* __restrict__ bproj,
                                              float* __restrict__ out)
{
    __shared__ short a_s[128 * 128];
    __shared__ short b_s[128 * 128];
    __shared__ float bias_s[128];
    int t = threadIdx.x;
    int b = blockIdx.y;
    int px0 = blockIdx.x * 128;
    const bf16* resl = qkvg + (size_t)(b * 256 + 192) * HW;

    if (t < 128) bias_s[t] = bproj[t];
    #pragma unroll
    for (int i = 0; i < 16; i++) {
        int idx = i * 1024 + t * 4;
        int row = idx >> 7, col = idx & 127;
        floatx4 wv = *(const floatx4*)(Wproj + row * 128 + col);
        short4v pk;
        pk[0] = f2bs(wv[0]); pk[1] = f2bs(wv[1]); pk[2] = f2bs(wv[2]); pk[3] = f2bs(wv[3]);
        *(short4v*)&a_s[row * 128 + col] = pk;
    }
    #pragma unroll
    for (int i = 0; i < 16; i++) {
        int idx = i * 1024 + t * 4;
        int c = idx >> 7, px = idx & 127;
        const short* src = (c < 64) ? (const short*)(resh + ((size_t)b * 64 + c) * HW + px0 + px)
                                    : (const short*)(resl + (size_t)(c - 64) * HW + px0 + px);
        short4v xv = *(const short4v*)src;
        #pragma unroll
        for (int e = 0; e < 4; e++)
            b_s[((c >> 3) * 128 + px + e) * 8 + (c & 7)] = xv[e];
    }
    __syncthreads();

    int wave = wuniform(t >> 6);
    int lane = t & 63;
    int quad = lane >> 4, l16 = lane & 15;
    floatx4 acc[2][8] = {};
    #pragma unroll
    for (int kk = 0; kk < 4; kk++) {
        short8v a0 = *(const short8v*)&a_s[(wave * 32 + l16) * 128 + kk * 32 + quad * 8];
        short8v a1 = *(const short8v*)&a_s[(wave * 32 + 16 + l16) * 128 + kk * 32 + quad * 8];
        #pragma unroll
        for (int nt = 0; nt < 8; nt++) {
            short8v bv = *(const short8v*)&b_s[((kk * 4 + quad) * 128 + nt * 16 + l16) * 8];
            acc[0][nt] = __builtin_amdgcn_mfma_f32_16x16x32_bf16(a0, bv, acc[0][nt], 0, 0, 0);
            acc[1][nt] = __builtin_amdgcn_mfma_f32_16x16x32_bf16(a1, bv, acc[1][nt], 0, 0, 0);
        }
    }
    #pragma unroll
    for (int m = 0; m < 2; m++) {
        int rowb = wave * 32 + m * 16 + quad * 4;
        #pragma unroll
        for (int nt = 0; nt < 8; nt++) {
            int px = px0 + nt * 16 + l16;
            #pragma unroll
            for (int r = 0; r < 4; r++) {
                int row = rowb + r;
                out[((size_t)b * 128 + row) * HW + px] = acc[m][nt][r] + bias_s[row];
            }
        }
    }
}

extern "C" void kernel_launch(void* const* d_in, const int* in_sizes, int n_in,
                              void* d_out, int out_size, void* d_ws, size_t ws_size,
                              hipStream_t stream)
{
    (void)in_sizes; (void)n_in; (void)out_size; (void)ws_size;
    const float* x     = (const float*)d_in[0];
    const float* Wqkv  = (const float*)d_in[1];
    const float* bqkv  = (const float*)d_in[2];
    const float* Wdw   = (const float*)d_in[3];
    const float* bdw   = (const float*)d_in[4];
    const float* Wa1   = (const float*)d_in[5];
    const float* ba1   = (const float*)d_in[6];
    const float* Wa2   = (const float*)d_in[7];
    const float* ba2   = (const float*)d_in[8];
    const float* Wq    = (const float*)d_in[9];
    const float* bq    = (const float*)d_in[10];
    const float* Wkv   = (const float*)d_in[11];
    const float* bkv   = (const float*)d_in[12];
    const float* Wproj = (const float*)d_in[13];
    const float* bproj = (const float*)d_in[14];

    char* wsb = (char*)d_ws;
    float* xp   = (float*)(wsb + OFFB_XP);
    float* k2   = (float*)(wsb + OFFB_K2);
    float* v2   = (float*)(wsb + OFFB_V2);
    bf16*  qkvg = (bf16*)(wsb + OFFB_QKVG);
    bf16*  resh = (bf16*)(wsb + OFFB_RESH);
    bf16*  p    = (bf16*)d_out;                  // scratch in d_out, dead before k_proj
    bf16*  v    = (bf16*)d_out + 4194304;
    float* out  = (float*)d_out;

    k_pool<<<dim3(512), 256, 0, stream>>>(x, xp);
    k_kv<<<dim3(64), 256, 0, stream>>>(xp, Wkv, bkv, k2, v2);
    k_conv<<<dim3(128, 2, 4), 256, 0, stream>>>(x, Wqkv, bqkv, Wq, bq, qkvg);
    k_dw<<<dim3(16384), 256, 0, stream>>>(qkvg, Wdw, bdw, p, v);
    k_attn<<<dim3(64, 4, 4), 256, 0, stream>>>(qkvg, k2, v2);       // res_l in-place over qg ch
    k_resh<<<dim3(1024), 256, 0, stream>>>(p, v, Wa1, ba1, Wa2, ba2, resh);
    k_proj<<<dim3(128, 4), 256, 0, stream>>>(resh, qkvg, Wproj, bproj, out);
}

// Round 8
// 255.711 us; speedup vs baseline: 3.0491x; 1.2187x over previous
//
#include <hip/hip_runtime.h>
#include <hip/hip_bf16.h>

typedef __hip_bfloat16 bf16;
typedef short short8v __attribute__((ext_vector_type(8)));
typedef short short4v __attribute__((ext_vector_type(4)));
typedef float floatx4 __attribute__((ext_vector_type(4)));

#define HW 16384

__device__ __forceinline__ float b2f(bf16 v) { return __bfloat162float(v); }
__device__ __forceinline__ bf16 f2b(float v) { return __float2bfloat16(v); }
__device__ __forceinline__ short f2bs(float v) { bf16 h = __float2bfloat16(v); return __builtin_bit_cast(short, h); }
__device__ __forceinline__ float bs2f(short s) { return b2f(__builtin_bit_cast(bf16, s)); }
__device__ __forceinline__ int wuniform(int v) { return __builtin_amdgcn_readfirstlane(v); }

// ---- ws byte offsets (total 41 MiB, proven safe) ----
#define OFFB_XP    0u
#define OFFB_K2    524288u
#define OFFB_V2    786432u
#define OFFB_QKVG  (1u << 20)         // bf16 (b,256,HW): 0-63 q, 64-127 k, 128-191 v, 192-255 qg->res_l
#define OFFB_RESH  (33u << 20)        // bf16 (b,64,HW)
// p / v-hat scratch in d_out [0,16MiB); d_out fully overwritten by k_proj.

// ---------------- 8x8 avgpool ----------------
__global__ __launch_bounds__(256) void k_pool(const float* __restrict__ x, float* __restrict__ xp)
{
    int idx = blockIdx.x * 256 + threadIdx.x;
    int j = idx & 15, i = (idx >> 4) & 15, bc = idx >> 8;
    const float* src = x + (size_t)bc * HW + (i * 8) * 128 + j * 8;
    float s = 0.f;
    #pragma unroll
    for (int u = 0; u < 8; u++) {
        #pragma unroll
        for (int t = 0; t < 8; t++) s += src[u * 128 + t];
    }
    xp[bc * 256 + i * 16 + j] = s * (1.f / 64.f);
}

// ---------------- kv conv: xp -> k2/v2 fp32 (b,h,m,d) ----------------
__global__ __launch_bounds__(256) void k_kv(const float* __restrict__ xp,
                                            const float* __restrict__ Wkv, const float* __restrict__ bkv,
                                            float* __restrict__ k2, float* __restrict__ v2)
{
    int og = blockIdx.x & 15, b = blockIdx.x >> 4;
    int m = threadIdx.x;
    float xr[128];
    #pragma unroll
    for (int c = 0; c < 128; c++) xr[c] = xp[(b * 128 + c) * 256 + m];
    #pragma unroll 1
    for (int t = 0; t < 8; t++) {
        int o = og * 8 + t;
        const float* w = Wkv + o * 128;
        float s0 = 0.f, s1 = 0.f, s2 = 0.f, s3 = 0.f;
        #pragma unroll
        for (int c = 0; c < 128; c += 4) {
            s0 += w[c] * xr[c]; s1 += w[c + 1] * xr[c + 1];
            s2 += w[c + 2] * xr[c + 2]; s3 += w[c + 3] * xr[c + 3];
        }
        float a = bkv[o] + ((s0 + s1) + (s2 + s3));
        int sb = o >> 6, r = o & 63, gh = r >> 4, dh = r & 15;
        float* dst = sb == 0 ? k2 : v2;
        dst[((b * 4 + gh) * 256 + m) * 16 + dh] = a;
    }
}

// ---------------- MFMA conv1x1: x -> qkvg bf16. grid (128 px-tiles, 2 m-blocks, 4 b) -----
__global__ __launch_bounds__(256) void k_conv(const float* __restrict__ x,
                                              const float* __restrict__ Wqkv, const float* __restrict__ bqkv,
                                              const float* __restrict__ Wq,  const float* __restrict__ bq,
                                              bf16* __restrict__ qkvg)
{
    __shared__ short a_s[128 * 128];          // A[oc][k] bf16
    __shared__ short b_s[128 * 128];          // B packed [k>>3][px][k&7] bf16
    __shared__ float bias_s[128];
    int t = threadIdx.x;
    int b = blockIdx.z, my = blockIdx.y;
    int px0 = blockIdx.x * 128;

    if (t < 128) {
        int oc = my * 128 + t;
        bias_s[t] = (oc < 192) ? bqkv[oc] : bq[oc - 192];
    }
    #pragma unroll
    for (int i = 0; i < 16; i++) {            // stage A: W fp32 -> bf16
        int idx = i * 1024 + t * 4;
        int row = idx >> 7, col = idx & 127;
        int oc = my * 128 + row;
        const float* src = (oc < 192) ? (Wqkv + oc * 128 + col) : (Wq + (oc - 192) * 128 + col);
        floatx4 wv = *(const floatx4*)src;
        short4v pk;
        pk[0] = f2bs(wv[0]); pk[1] = f2bs(wv[1]); pk[2] = f2bs(wv[2]); pk[3] = f2bs(wv[3]);
        *(short4v*)&a_s[row * 128 + col] = pk;
    }
    #pragma unroll
    for (int i = 0; i < 16; i++) {            // stage B: x fp32 -> packed bf16
        int idx = i * 1024 + t * 4;
        int c = idx >> 7, px = idx & 127;
        floatx4 xv = *(const floatx4*)(x + ((size_t)b * 128 + c) * HW + px0 + px);
        #pragma unroll
        for (int e = 0; e < 4; e++)
            b_s[((c >> 3) * 128 + px + e) * 8 + (c & 7)] = f2bs(xv[e]);
    }
    __syncthreads();

    int wave = wuniform(t >> 6);
    int lane = t & 63;
    int quad = lane >> 4, l16 = lane & 15;
    floatx4 acc[2][8] = {};
    #pragma unroll
    for (int kk = 0; kk < 4; kk++) {
        short8v a0 = *(const short8v*)&a_s[(wave * 32 + l16) * 128 + kk * 32 + quad * 8];
        short8v a1 = *(const short8v*)&a_s[(wave * 32 + 16 + l16) * 128 + kk * 32 + quad * 8];
        #pragma unroll
        for (int nt = 0; nt < 8; nt++) {
            short8v bv = *(const short8v*)&b_s[((kk * 4 + quad) * 128 + nt * 16 + l16) * 8];
            acc[0][nt] = __builtin_amdgcn_mfma_f32_16x16x32_bf16(a0, bv, acc[0][nt], 0, 0, 0);
            acc[1][nt] = __builtin_amdgcn_mfma_f32_16x16x32_bf16(a1, bv, acc[1][nt], 0, 0, 0);
        }
    }
    #pragma unroll
    for (int m = 0; m < 2; m++) {
        int rowb = wave * 32 + m * 16 + quad * 4;
        #pragma unroll
        for (int nt = 0; nt < 8; nt++) {
            int px = px0 + nt * 16 + l16;
            #pragma unroll
            for (int r = 0; r < 4; r++) {
                int row = rowb + r;
                float val = acc[m][nt][r] + bias_s[row];
                qkvg[((size_t)b * 256 + my * 128 + row) * HW + px] = f2b(val);
            }
        }
    }
}

// ---------------- depthwise 3x3 + q*k, vectorized: 8 px/thread. grid 2048 ----------------
__global__ __launch_bounds__(256) void k_dw(const bf16* __restrict__ qkvg,
                                            const float* __restrict__ Wdw, const float* __restrict__ bdw,
                                            bf16* __restrict__ p, bf16* __restrict__ v)
{
    int blk = blockIdx.x;            // 2048
    int bc = blk >> 3;               // b*64+c
    int c = bc & 63, b = bc >> 6;
    int g = (blk & 7) * 256 + threadIdx.x;   // 0..2047 pixel-groups in plane
    int i = g >> 4;                  // row
    int j0 = (g & 15) * 8;           // col start
    float acc[3][8];
    #pragma unroll
    for (int pl = 0; pl < 3; pl++) {
        float bias = bdw[pl * 64 + c];
        #pragma unroll
        for (int t2 = 0; t2 < 8; t2++) acc[pl][t2] = bias;
    }
    #pragma unroll
    for (int pl = 0; pl < 3; pl++) {
        const bf16* plane = qkvg + (size_t)(b * 256 + pl * 64 + c) * HW;
        const float* w = Wdw + (pl * 64 + c) * 9;
        #pragma unroll
        for (int dy = 0; dy < 3; dy++) {
            int ii = i + dy - 1;
            float e[10];
            if ((unsigned)ii < 128u) {
                const bf16* r = plane + ii * 128 + j0;
                short8v v8 = *(const short8v*)r;
                #pragma unroll
                for (int t2 = 0; t2 < 8; t2++) e[t2 + 1] = bs2f(v8[t2]);
                e[0] = (j0 > 0) ? b2f(r[-1]) : 0.f;
                e[9] = (j0 < 120) ? b2f(r[8]) : 0.f;
            } else {
                #pragma unroll
                for (int t2 = 0; t2 < 10; t2++) e[t2] = 0.f;
            }
            float wa = w[dy * 3], wb = w[dy * 3 + 1], wc = w[dy * 3 + 2];
            #pragma unroll
            for (int t2 = 0; t2 < 8; t2++)
                acc[pl][t2] += wa * e[t2] + wb * e[t2 + 1] + wc * e[t2 + 2];
        }
    }
    short8v pv, vv;
    #pragma unroll
    for (int t2 = 0; t2 < 8; t2++) {
        pv[t2] = f2bs(acc[0][t2] * acc[1][t2]);
        vv[t2] = f2bs(acc[2][t2]);
    }
    size_t off = (size_t)(b * 64 + c) * HW + i * 128 + j0;
    *(short8v*)(p + off) = pv;
    *(short8v*)(v + off) = vv;
}

// ---------------- MFMA low-freq attention. grid (64 px-blocks, 4 h, 4 b) ----------------
__global__ __launch_bounds__(256) void k_attn(bf16* __restrict__ qkvg, const float* __restrict__ k2,
                                              const float* __restrict__ v2)
{
    __shared__ short kt[16 * 64 * 8];
    __shared__ short vt[8 * 64 * 8];
    __shared__ short un[32 * 64 * 8];
    int t = threadIdx.x;
    int h = blockIdx.y, b = blockIdx.z;
    int px0b = blockIdx.x * 256;
    const float* K = k2 + (size_t)(b * 4 + h) * 4096;
    const float* V = v2 + (size_t)(b * 4 + h) * 4096;
    bf16* Qbase = qkvg + (size_t)(b * 256 + 192 + h * 16) * HW + px0b;

    {
        int mt = t >> 4, l16k = t & 15;
        float4 k0 = *(const float4*)(K + t * 16);
        float4 k1 = *(const float4*)(K + t * 16 + 4);
        float4 kx2 = *(const float4*)(K + t * 16 + 8);
        float4 k3 = *(const float4*)(K + t * 16 + 12);
        short8v lo, hi, zz = {};
        lo[0] = f2bs(k0.x); lo[1] = f2bs(k0.y); lo[2] = f2bs(k0.z); lo[3] = f2bs(k0.w);
        lo[4] = f2bs(k1.x); lo[5] = f2bs(k1.y); lo[6] = f2bs(k1.z); lo[7] = f2bs(k1.w);
        hi[0] = f2bs(kx2.x); hi[1] = f2bs(kx2.y); hi[2] = f2bs(kx2.z); hi[3] = f2bs(kx2.w);
        hi[4] = f2bs(k3.x); hi[5] = f2bs(k3.y); hi[6] = f2bs(k3.z); hi[7] = f2bs(k3.w);
        *(short8v*)&kt[(mt * 64 + l16k) * 8] = lo;
        *(short8v*)&kt[(mt * 64 + 16 + l16k) * 8] = hi;
        *(short8v*)&kt[(mt * 64 + 32 + l16k) * 8] = zz;
        *(short8v*)&kt[(mt * 64 + 48 + l16k) * 8] = zz;
    }
    #pragma unroll
    for (int u = 0; u < 2; u++) {
        int f = t * 2 + u;
        int mb = f >> 6, lane = f & 63, quad = lane >> 4, d = lane & 15;
        short8v pk;
        #pragma unroll
        for (int i = 0; i < 8; i++) pk[i] = f2bs(V[(mb * 32 + quad * 8 + i) * 16 + d]);
        *(short8v*)&vt[f * 8] = pk;
    }
    #pragma unroll
    for (int u = 0; u < 4; u++) {
        int f = t * 4 + u;
        int pxt = f >> 6, lane = f & 63, quad = lane >> 4, l16 = lane & 15;
        int px = pxt * 16 + l16;
        short8v pk = {};
        if (quad < 2) {
            #pragma unroll
            for (int i = 0; i < 8; i++)
                pk[i] = f2bs(b2f(Qbase[(size_t)(quad * 8 + i) * HW + px]) * 0.25f);
        }
        *(short8v*)&un[f * 8] = pk;
    }
    __syncthreads();

    int wave = wuniform(t >> 6);
    int lane = t & 63;
    int quad = lane >> 4, l16 = lane & 15;
    short8v qf[4];
    #pragma unroll
    for (int u = 0; u < 4; u++)
        qf[u] = *(const short8v*)&un[((wave * 4 + u) * 64 + lane) * 8];
    __syncthreads();

    #pragma unroll 1
    for (int u = 0; u < 4; u++) {
        int pxt = wave * 4 + u;
        floatx4 sc[16];
        #pragma unroll
        for (int mt = 0; mt < 16; mt++) {
            short8v kf = *(const short8v*)&kt[(mt * 64 + lane) * 8];
            sc[mt] = __builtin_amdgcn_mfma_f32_16x16x32_bf16(kf, qf[u], (floatx4){0.f, 0.f, 0.f, 0.f}, 0, 0, 0);
        }
        float den = 0.f;
        #pragma unroll
        for (int mt = 0; mt < 16; mt++) {
            short4v pk;
            #pragma unroll
            for (int r = 0; r < 4; r++) {
                float s = fminf(fmaxf(sc[mt][r], -60.f), 60.f);
                short pb = f2bs(__expf(s));
                pk[r] = pb;
                den += bs2f(pb);
            }
            int mwin = (mt & 1) * 16 + quad * 4;
            int lane_d = (mwin >> 3) * 16 + l16;
            *(short4v*)&un[((wave * 8 + (mt >> 1)) * 64 + lane_d) * 8 + (mwin & 7)] = pk;
        }
        den += __shfl_xor(den, 16, 64);
        den += __shfl_xor(den, 32, 64);
        float rden = 1.f / den;
        floatx4 oa = {};
        #pragma unroll
        for (int mb = 0; mb < 8; mb++) {
            short8v vf = *(const short8v*)&vt[(mb * 64 + lane) * 8];
            short8v pf = *(const short8v*)&un[((wave * 8 + mb) * 64 + lane) * 8];
            oa = __builtin_amdgcn_mfma_f32_16x16x32_bf16(vf, pf, oa, 0, 0, 0);
        }
        #pragma unroll
        for (int r = 0; r < 4; r++)
            Qbase[(size_t)(quad * 4 + r) * HW + pxt * 16 + l16] = f2b(oa[r] * rden);
    }
}

// ---------------- MFMA high-freq gate: p,v-hat -> res_h. grid (128 px-tiles, 4 b) --------
// GEMM1 (Wa1 64x64 · P) -> swish -> repack -> GEMM2 (Wa2 64x64) -> tanh*vhat
__global__ __launch_bounds__(256) void k_resh(const bf16* __restrict__ p, const bf16* __restrict__ vhat,
                                              const float* __restrict__ Wa1, const float* __restrict__ ba1,
                                              const float* __restrict__ Wa2, const float* __restrict__ ba2,
                                              bf16* __restrict__ resh)
{
    __shared__ short aw1[64 * 64];       // A1[oc][ic]
    __shared__ short aw2[64 * 64];       // A2[oc][ic]
    __shared__ short bp[8 * 128 * 8];    // P  packed [ic>>3][px][ic&7]
    __shared__ short bs2[8 * 128 * 8];   // swish packed (same layout)
    __shared__ float b1s[64], b2s[64];
    int t = threadIdx.x;
    int b = blockIdx.y;
    int px0 = blockIdx.x * 128;

    if (t < 64) { b1s[t] = ba1[t]; b2s[t] = ba2[t]; }
    #pragma unroll
    for (int i = 0; i < 4; i++) {        // stage Wa1/Wa2 fp32->bf16 (4096 each)
        int idx = i * 1024 + t * 4;
        floatx4 w1 = *(const floatx4*)(Wa1 + idx);
        floatx4 w2 = *(const floatx4*)(Wa2 + idx);
        short4v p1, p2;
        #pragma unroll
        for (int e = 0; e < 4; e++) { p1[e] = f2bs(w1[e]); p2[e] = f2bs(w2[e]); }
        *(short4v*)&aw1[idx] = p1;
        *(short4v*)&aw2[idx] = p2;
    }
    #pragma unroll
    for (int i = 0; i < 8; i++) {        // stage P tile packed (8192 shorts)
        int idx = i * 1024 + t * 4;
        int cc = idx >> 7, px = idx & 127;
        short4v xv = *(const short4v*)((const short*)p + (size_t)(b * 64 + cc) * HW + px0 + px);
        #pragma unroll
        for (int e = 0; e < 4; e++)
            bp[((cc >> 3) * 128 + px + e) * 8 + (cc & 7)] = xv[e];
    }
    __syncthreads();

    int wave = wuniform(t >> 6);         // = mtile (M=64 -> 4 mtiles)
    int lane = t & 63;
    int quad = lane >> 4, l16 = lane & 15;
    int k0 = wave * 16 + quad * 4;       // output-channel base for this lane's C rows

    floatx4 acc1[8] = {};
    #pragma unroll
    for (int kk = 0; kk < 2; kk++) {
        short8v af = *(const short8v*)&aw1[(wave * 16 + l16) * 64 + kk * 32 + quad * 8];
        #pragma unroll
        for (int nt = 0; nt < 8; nt++) {
            short8v bf = *(const short8v*)&bp[((kk * 4 + quad) * 128 + nt * 16 + l16) * 8];
            acc1[nt] = __builtin_amdgcn_mfma_f32_16x16x32_bf16(af, bf, acc1[nt], 0, 0, 0);
        }
    }
    #pragma unroll
    for (int nt = 0; nt < 8; nt++) {     // swish + repack C-layout -> B-frag layout
        int px = nt * 16 + l16;
        short4v pk;
        #pragma unroll
        for (int r = 0; r < 4; r++) {
            float a = acc1[nt][r] + b1s[k0 + r];
            pk[r] = f2bs(a / (1.f + __expf(-a)));
        }
        *(short4v*)&bs2[((k0 >> 3) * 128 + px) * 8 + (k0 & 7)] = pk;
    }
    __syncthreads();

    floatx4 acc2[8] = {};
    #pragma unroll
    for (int kk = 0; kk < 2; kk++) {
        short8v af = *(const short8v*)&aw2[(wave * 16 + l16) * 64 + kk * 32 + quad * 8];
        #pragma unroll
        for (int nt = 0; nt < 8; nt++) {
            short8v bf = *(const short8v*)&bs2[((kk * 4 + quad) * 128 + nt * 16 + l16) * 8];
            acc2[nt] = __builtin_amdgcn_mfma_f32_16x16x32_bf16(af, bf, acc2[nt], 0, 0, 0);
        }
    }
    #pragma unroll
    for (int nt = 0; nt < 8; nt++) {
        int px = px0 + nt * 16 + l16;
        #pragma unroll
        for (int r = 0; r < 4; r++) {
            int oc = k0 + r;
            float g = tanhf((acc2[nt][r] + b2s[oc]) * 0.25f);
            float vv = b2f(vhat[(size_t)(b * 64 + oc) * HW + px]);
            resh[(size_t)(b * 64 + oc) * HW + px] = f2b(g * vv);
        }
    }
}

// ---------------- MFMA final proj: [res_h|res_l] -> out fp32. grid (128 px-tiles, 4 b) ---
__global__ __launch_bounds__(256) void k_proj(const bf16* __restrict__ resh, const bf16* __restrict__ qkvg,
                                              const float* __restrict__ Wproj, const float* __restrict__ bproj,
                                              float* __restrict__ out)
{
    __shared__ short a_s[128 * 128];
    __shared__ short b_s[128 * 128];
    __shared__ float bias_s[128];
    int t = threadIdx.x;
    int b = blockIdx.y;
    int px0 = blockIdx.x * 128;
    const bf16* resl = qkvg + (size_t)(b * 256 + 192) * HW;

    if (t < 128) bias_s[t] = bproj[t];
    #pragma unroll
    for (int i = 0; i < 16; i++) {
        int idx = i * 1024 + t * 4;
        int row = idx >> 7, col = idx & 127;
        floatx4 wv = *(const floatx4*)(Wproj + row * 128 + col);
        short4v pk;
        pk[0] = f2bs(wv[0]); pk[1] = f2bs(wv[1]); pk[2] = f2bs(wv[2]); pk[3] = f2bs(wv[3]);
        *(short4v*)&a_s[row * 128 + col] = pk;
    }
    #pragma unroll
    for (int i = 0; i < 16; i++) {
        int idx = i * 1024 + t * 4;
        int c = idx >> 7, px = idx & 127;
        const short* src = (c < 64) ? (const short*)(resh + ((size_t)b * 64 + c) * HW + px0 + px)
                                    : (const short*)(resl + (size_t)(c - 64) * HW + px0 + px);
        short4v xv = *(const short4v*)src;
        #pragma unroll
        for (int e = 0; e < 4; e++)
            b_s[((c >> 3) * 128 + px + e) * 8 + (c & 7)] = xv[e];
    }
    __syncthreads();

    int wave = wuniform(t >> 6);
    int lane = t & 63;
    int quad = lane >> 4, l16 = lane & 15;
    floatx4 acc[2][8] = {};
    #pragma unroll
    for (int kk = 0; kk < 4; kk++) {
        short8v a0 = *(const short8v*)&a_s[(wave * 32 + l16) * 128 + kk * 32 + quad * 8];
        short8v a1 = *(const short8v*)&a_s[(wave * 32 + 16 + l16) * 128 + kk * 32 + quad * 8];
        #pragma unroll
        for (int nt = 0; nt < 8; nt++) {
            short8v bv = *(const short8v*)&b_s[((kk * 4 + quad) * 128 + nt * 16 + l16) * 8];
            acc[0][nt] = __builtin_amdgcn_mfma_f32_16x16x32_bf16(a0, bv, acc[0][nt], 0, 0, 0);
            acc[1][nt] = __builtin_amdgcn_mfma_f32_16x16x32_bf16(a1, bv, acc[1][nt], 0, 0, 0);
        }
    }
    #pragma unroll
    for (int m = 0; m < 2; m++) {
        int rowb = wave * 32 + m * 16 + quad * 4;
        #pragma unroll
        for (int nt = 0; nt < 8; nt++) {
            int px = px0 + nt * 16 + l16;
            #pragma unroll
            for (int r = 0; r < 4; r++) {
                int row = rowb + r;
                out[((size_t)b * 128 + row) * HW + px] = acc[m][nt][r] + bias_s[row];
            }
        }
    }
}

extern "C" void kernel_launch(void* const* d_in, const int* in_sizes, int n_in,
                              void* d_out, int out_size, void* d_ws, size_t ws_size,
                              hipStream_t stream)
{
    (void)in_sizes; (void)n_in; (void)out_size; (void)ws_size;
    const float* x     = (const float*)d_in[0];
    const float* Wqkv  = (const float*)d_in[1];
    const float* bqkv  = (const float*)d_in[2];
    const float* Wdw   = (const float*)d_in[3];
    const float* bdw   = (const float*)d_in[4];
    const float* Wa1   = (const float*)d_in[5];
    const float* ba1   = (const float*)d_in[6];
    const float* Wa2   = (const float*)d_in[7];
    const float* ba2   = (const float*)d_in[8];
    const float* Wq    = (const float*)d_in[9];
    const float* bq    = (const float*)d_in[10];
    const float* Wkv   = (const float*)d_in[11];
    const float* bkv   = (const float*)d_in[12];
    const float* Wproj = (const float*)d_in[13];
    const float* bproj = (const float*)d_in[14];

    char* wsb = (char*)d_ws;
    float* xp   = (float*)(wsb + OFFB_XP);
    float* k2   = (float*)(wsb + OFFB_K2);
    float* v2   = (float*)(wsb + OFFB_V2);
    bf16*  qkvg = (bf16*)(wsb + OFFB_QKVG);
    bf16*  resh = (bf16*)(wsb + OFFB_RESH);
    bf16*  p    = (bf16*)d_out;                  // scratch in d_out, dead before k_proj
    bf16*  v    = (bf16*)d_out + 4194304;
    float* out  = (float*)d_out;

    k_pool<<<dim3(512), 256, 0, stream>>>(x, xp);
    k_kv<<<dim3(64), 256, 0, stream>>>(xp, Wkv, bkv, k2, v2);
    k_conv<<<dim3(128, 2, 4), 256, 0, stream>>>(x, Wqkv, bqkv, Wq, bq, qkvg);
    k_dw<<<dim3(2048), 256, 0, stream>>>(qkvg, Wdw, bdw, p, v);
    k_attn<<<dim3(64, 4, 4), 256, 0, stream>>>(qkvg, k2, v2);       // res_l in-place over qg ch
    k_resh<<<dim3(128, 4), 256, 0, stream>>>(p, v, Wa1, ba1, Wa2, ba2, resh);
    k_proj<<<dim3(128, 4), 256, 0, stream>>>(resh, qkvg, Wproj, bproj, out);
}